// Round 11
// baseline (252.081 us; speedup 1.0000x reference)
//
#include <hip/hip_runtime.h>
#include <hip/hip_bf16.h>
#include <math.h>

#define S_LEN 2048
#define DMODEL 2048
#define NHEADS 16
#define HDIM 128

typedef __bf16 bf16x8 __attribute__((ext_vector_type(8)));
typedef float f32x4 __attribute__((ext_vector_type(4)));
typedef float f32x16 __attribute__((ext_vector_type(16)));

__device__ __forceinline__ unsigned short f2b(float f) {
  union { float f; unsigned u; } c; c.f = f;
  unsigned r = (c.u + 0x7fffu + ((c.u >> 16) & 1u)) >> 16;
  return (unsigned short)r;
}
__device__ __forceinline__ float b2f(unsigned short b) {
  union { unsigned u; float f; } c; c.u = ((unsigned)b) << 16;
  return c.f;
}

__device__ __forceinline__ void gload_lds16(const unsigned short* g, unsigned short* l) {
  __builtin_amdgcn_global_load_lds(
      (__attribute__((address_space(1))) void*)(void*)g,
      (__attribute__((address_space(3))) void*)(void*)l, 16, 0, 0);
}

// ---------------- fused fp32 -> bf16 conversion (5 tensors, one launch) ----
__global__ void cvt5_f32_bf16_k(const float* __restrict__ s0,
                                const float* __restrict__ s1,
                                const float* __restrict__ s2,
                                const float* __restrict__ s3,
                                const float* __restrict__ s4,
                                unsigned short* __restrict__ d0,
                                unsigned short* __restrict__ d1,
                                unsigned short* __restrict__ d2,
                                unsigned short* __restrict__ d3,
                                unsigned short* __restrict__ d4) {
  int gi = blockIdx.x * blockDim.x + threadIdx.x;
  int seg = gi >> 20;
  int i = (gi & 0xFFFFF) * 4;
  const float* src = (seg == 0) ? s0 : (seg == 1) ? s1 : (seg == 2) ? s2
                     : (seg == 3) ? s3 : s4;
  unsigned short* dst = (seg == 0) ? d0 : (seg == 1) ? d1 : (seg == 2) ? d2
                        : (seg == 3) ? d3 : d4;
  float4 v = *reinterpret_cast<const float4*>(src + i);
  ushort4 o;
  o.x = f2b(v.x); o.y = f2b(v.y); o.z = f2b(v.z); o.w = f2b(v.w);
  *reinterpret_cast<ushort4*>(dst + i) = o;
}

// ---------------- RoPE cos/sin table ----------------
__global__ void rope_table_k(float* __restrict__ cs, float* __restrict__ sn) {
  int idx = blockIdx.x * blockDim.x + threadIdx.x;  // S_LEN * 64
  int s = idx >> 6, i = idx & 63;
  float inv = powf(10000.0f, -(float)(2 * i) / 128.0f);
  float a = (float)s * inv;
  cs[idx] = cosf(a);
  sn[idx] = sinf(a);
}

// ---------------- RoPE apply (in-place on q,k bf16) ----------------
// q additionally scaled by sm*log2(e): softmax runs in log2 domain.
__global__ void rope_apply_k(unsigned short* __restrict__ q,
                             unsigned short* __restrict__ k,
                             const float* __restrict__ cs,
                             const float* __restrict__ sn) {
  const float SC = 0.08838834764831845f * 1.4426950408889634f;  // sm * log2e
  int idx = blockIdx.x * blockDim.x + threadIdx.x;  // S*H*64
  int i = idx & 63;
  int h = (idx >> 6) & (NHEADS - 1);
  int s = idx >> 10;
  size_t base = (size_t)s * DMODEL + h * HDIM;
  float c = cs[s * 64 + i], sv = sn[s * 64 + i];
  float qc = c * SC, qs = sv * SC;
  float q1 = b2f(q[base + i]), q2 = b2f(q[base + i + 64]);
  q[base + i]      = f2b(q1 * qc - q2 * qs);
  q[base + i + 64] = f2b(q2 * qc + q1 * qs);
  float k1 = b2f(k[base + i]), k2 = b2f(k[base + i + 64]);
  k[base + i]      = f2b(k1 * c - k2 * sv);
  k[base + i + 64] = f2b(k2 * c + k1 * sv);
}

// ---------------- bf16 2048x2048 transpose ----------------
__global__ __launch_bounds__(256) void transpose_bf16_k(
    const unsigned short* __restrict__ in, unsigned short* __restrict__ out) {
  __shared__ unsigned short tile[64][72];
  int bx = blockIdx.x, by = blockIdx.y;
  int t = threadIdx.x;
#pragma unroll
  for (int i = 0; i < 2; ++i) {
    int ch = i * 256 + t;
    int r = ch >> 3, c8 = ch & 7;
    bf16x8 v = *reinterpret_cast<const bf16x8*>(
        in + (size_t)(by * 64 + r) * DMODEL + bx * 64 + c8 * 8);
    *reinterpret_cast<bf16x8*>(&tile[r][c8 * 8]) = v;
  }
  __syncthreads();
#pragma unroll
  for (int i = 0; i < 2; ++i) {
    int ch = i * 256 + t;
    int c = ch >> 3, r8 = ch & 7;
    union { bf16x8 v; unsigned short u[8]; } w;
#pragma unroll
    for (int j = 0; j < 8; ++j) w.u[j] = tile[r8 * 8 + j][c];
    *reinterpret_cast<bf16x8*>(
        out + (size_t)(bx * 64 + c) * S_LEN + by * 64 + r8 * 8) = w.v;
  }
}

// ============ 8-phase 256-wide NT GEMM (unchanged, verified) ============

#define MIDBAR_SEQ()                                      \
  do {                                                    \
    asm volatile("" ::: "memory");                        \
    __builtin_amdgcn_s_barrier();                         \
    asm volatile("s_waitcnt lgkmcnt(0)" ::: "memory");    \
    __builtin_amdgcn_sched_barrier(0);                    \
    __builtin_amdgcn_s_setprio(1);                        \
  } while (0)

#define ENDBAR_SEQ()                                      \
  do {                                                    \
    __builtin_amdgcn_s_setprio(0);                        \
    asm volatile("" ::: "memory");                        \
    __builtin_amdgcn_s_barrier();                         \
    asm volatile("" ::: "memory");                        \
  } while (0)

#define READA(QM)                                                              \
  do {                                                                         \
    _Pragma("unroll") for (int j = 0; j < MQ; ++j)                             \
    _Pragma("unroll") for (int kk = 0; kk < 2; ++kk) {                         \
      int row = wm * (BM / 2) + ((QM) * MQ + j) * 16 + li;                     \
      int c = (kk * 4 + g) ^ (li & 7);                                         \
      af[j][kk] = *reinterpret_cast<const bf16x8*>(&As[cur][row * 64 + c * 8]);\
    }                                                                          \
  } while (0)

#define READB(BF, QN)                                                          \
  do {                                                                         \
    _Pragma("unroll") for (int jn = 0; jn < 2; ++jn)                           \
    _Pragma("unroll") for (int kk = 0; kk < 2; ++kk) {                         \
      int row = wn * 64 + ((QN) * 2 + jn) * 16 + li;                           \
      int c = (kk * 4 + g) ^ (li & 7);                                         \
      BF[jn][kk] = *reinterpret_cast<const bf16x8*>(&Bs[cur][row * 64 + c * 8]);\
    }                                                                          \
  } while (0)

#define QUAD(QM, QN, BF)                                                       \
  do {                                                                         \
    _Pragma("unroll") for (int j = 0; j < MQ; ++j)                             \
    _Pragma("unroll") for (int jn = 0; jn < 2; ++jn)                           \
    _Pragma("unroll") for (int kk = 0; kk < 2; ++kk)                           \
      acc[(QM) * MQ + j][(QN) * 2 + jn] =                                      \
          __builtin_amdgcn_mfma_f32_16x16x32_bf16(                             \
              af[j][kk], BF[jn][kk], acc[(QM) * MQ + j][(QN) * 2 + jn], 0, 0, 0);\
  } while (0)

template <int BM, bool OUT_F32>
__global__ __launch_bounds__(512, 2) void gemm_8ph_k(
    const unsigned short* __restrict__ A, const unsigned short* __restrict__ B0p,
    const unsigned short* __restrict__ B1p, const unsigned short* __restrict__ B2p,
    void* __restrict__ C0, void* __restrict__ C1, void* __restrict__ C2,
    int M, int N, int K) {
  constexpr int MQ = BM / 64;
  constexpr int MR = BM / 32;

  __shared__ unsigned short As[2][BM * 64];
  __shared__ unsigned short Bs[2][256 * 64];

  const unsigned short* Bp = (blockIdx.z == 0) ? B0p : (blockIdx.z == 1) ? B1p : B2p;
  void* Cout = (blockIdx.z == 0) ? C0 : (blockIdx.z == 1) ? C1 : C2;

  int nwg = gridDim.x, bid = blockIdx.x;
  int wg = (bid & 7) * (nwg >> 3) + (bid >> 3);
  int ntn = N >> 8;
  int tm = wg / ntn, tn = wg % ntn;
  int m0 = tm * BM, n0 = tn << 8;

  const int tid = threadIdx.x;
  const int wave = tid >> 6, lane = tid & 63;
  const int g = lane >> 4, li = lane & 15;
  const int wm = wave >> 2, wn = wave & 3;

  auto stageB = [&](int buf, int tt, int qn) {
#pragma unroll
    for (int i = 0; i < 2; ++i) {
      int j = i * 512 + tid;
      int piece = j >> 8, rowin = (j >> 3) & 31, c = j & 7;
      int row = piece * 64 + qn * 32 + rowin;
      gload_lds16(Bp + (size_t)(n0 + row) * K + tt * 64 + ((c ^ (row & 7)) * 8),
                  &Bs[buf][row * 64 + c * 8]);
    }
  };
  auto stageA = [&](int buf, int tt, int qm) {
#pragma unroll
    for (int i = 0; i < BM / 128; ++i) {
      int j = i * 512 + tid;
      int piece = j / (2 * BM);
      int rowin = (j >> 3) & (BM / 4 - 1);
      int c = j & 7;
      int row = piece * (BM / 2) + qm * (BM / 4) + rowin;
      gload_lds16(A + (size_t)(m0 + row) * K + tt * 64 + ((c ^ (row & 7)) * 8),
                  &As[buf][row * 64 + c * 8]);
    }
  };

  f32x4 acc[MR][4];
#pragma unroll
  for (int i = 0; i < MR; ++i)
#pragma unroll
    for (int j = 0; j < 4; ++j) acc[i][j] = (f32x4){0.f, 0.f, 0.f, 0.f};

  const int nK = K >> 6;

  stageB(0, 0, 0); stageA(0, 0, 0); stageB(0, 0, 1); stageA(0, 0, 1);
  stageB(1, 1, 0); stageA(1, 1, 0); stageB(1, 1, 1); stageA(1, 1, 1);
  if constexpr (BM == 256) asm volatile("s_waitcnt vmcnt(8)" ::: "memory");
  else                     asm volatile("s_waitcnt vmcnt(6)" ::: "memory");
  asm volatile("" ::: "memory");
  __builtin_amdgcn_s_barrier();
  asm volatile("" ::: "memory");

  for (int t = 0; t < nK; ++t) {
    int cur = t & 1;
    bool pf = (t + 2 < nK);
    bf16x8 af[MQ][2], bf0[2][2], bf1[2][2];
    READA(0);
    READB(bf0, 0);
    MIDBAR_SEQ();
    QUAD(0, 0, bf0);
    ENDBAR_SEQ();
    READB(bf1, 1);
    if (pf) { stageB(cur, t + 2, 0); stageA(cur, t + 2, 0); }
    MIDBAR_SEQ();
    QUAD(0, 1, bf1);
    ENDBAR_SEQ();
    READA(1);
    if (pf) stageB(cur, t + 2, 1);
    MIDBAR_SEQ();
    QUAD(1, 1, bf1);
    ENDBAR_SEQ();
    if (pf) {
      stageA(cur, t + 2, 1);
      if constexpr (BM == 256) asm volatile("s_waitcnt vmcnt(8)" ::: "memory");
      else                     asm volatile("s_waitcnt vmcnt(6)" ::: "memory");
    } else {
      asm volatile("s_waitcnt vmcnt(0)" ::: "memory");
    }
    MIDBAR_SEQ();
    QUAD(1, 0, bf0);
    ENDBAR_SEQ();
  }

#pragma unroll
  for (int m = 0; m < MR; ++m) {
#pragma unroll
    for (int n = 0; n < 4; ++n) {
      int row = m0 + wm * (BM / 2) + m * 16 + g * 4;
      int col = n0 + wn * 64 + n * 16 + li;
#pragma unroll
      for (int r = 0; r < 4; ++r) {
        if (OUT_F32)
          reinterpret_cast<float*>(Cout)[(size_t)(row + r) * N + col] = acc[m][n][r];
        else
          reinterpret_cast<unsigned short*>(Cout)[(size_t)(row + r) * N + col] =
              f2b(acc[m][n][r]);
      }
    }
  }
}

#undef MIDBAR_SEQ
#undef ENDBAR_SEQ
#undef READA
#undef READB
#undef QUAD

// ---------------- causal flash attention v9: wave-private, ZERO barriers ----
// 256 blocks x 4 waves; each wave fully independent: own 32-row q-slice, own
// 32 KB double-buffered K/V LDS staging (4 x 32 = 128 KB), per-wave counted
// vmcnt. No s_barrier anywhere. Swapped 32x32 MFMA + in-register softmax
// (v8-verified layouts). kv-tile = 32 rows. Balance: block k = {h = k&15,
// g = k>>4}; waves take slices {2g, 2g+1, 62-2g, 63-2g} -> per-block chain
// sum = 130 tiles uniform. h = k&15 keeps 2 heads per XCD (L2 locality).
__global__ __launch_bounds__(256) void flash_attn_k(
    const unsigned short* __restrict__ q, const unsigned short* __restrict__ k,
    const unsigned short* __restrict__ vt, unsigned short* __restrict__ o) {
  __shared__ unsigned short lds[4][2][8192];  // [wave][buf][K 8KB | V 8KB]

  int bk = blockIdx.x;
  int h = bk & 15;
  int g = bk >> 4;

  int t = threadIdx.x, wave = t >> 6, l = t & 63;
  int l5 = l >> 5, l31 = l & 31;
  int sl = (wave == 0) ? 2 * g : (wave == 1) ? 2 * g + 1
           : (wave == 2) ? 62 - 2 * g : 63 - 2 * g;
  int q0w = sl * 32;
  int q_abs = q0w + l31;
  int nt = sl + 1;  // 32-row kv tiles

  const unsigned short* vth = vt + (size_t)h * HDIM * S_LEN;

  // wave-private stage of one 32-kv tile (16 gload_lds, coalesced)
  auto stage = [&](int buf, int tt) {
    int kv0 = tt * 32;
    unsigned short* Kb = &lds[wave][buf][0];
    unsigned short* Vb = &lds[wave][buf][4096];
#pragma unroll
    for (int i = 0; i < 8; ++i) {  // K: 32 rows x 16 chunks
      int ch = i * 64 + l;
      int row = ch >> 4, c = ch & 15;
      gload_lds16(k + (size_t)(kv0 + row) * DMODEL + h * HDIM + ((c ^ (row & 7)) * 8),
                  Kb + ch * 8);
    }
#pragma unroll
    for (int i = 0; i < 8; ++i) {  // V^T: 128 rows x 4 chunks
      int ch = i * 64 + l;
      int row = ch >> 2, c = ch & 3;
      gload_lds16(vth + (size_t)row * S_LEN + kv0 + ((c ^ (row & 3)) * 8),
                  Vb + ch * 8);
    }
  };

  // Q as B-operand: B[col=q=l31][k=d = kb*16 + l5*8 + b]
  bf16x8 qf[8];
#pragma unroll
  for (int kb = 0; kb < 8; ++kb)
    qf[kb] = *reinterpret_cast<const bf16x8*>(
        q + (size_t)q_abs * DMODEL + h * HDIM + kb * 16 + l5 * 8);

  f32x16 OT[4];
#pragma unroll
  for (int nf = 0; nf < 4; ++nf)
#pragma unroll
    for (int r = 0; r < 16; ++r) OT[nf][r] = 0.f;
  float m_r = -1e30f, l_r = 0.f;

  stage(0, 0);

  for (int tt = 0; tt < nt; ++tt) {
    int cur = tt & 1;
    if (tt + 1 < nt) {
      stage(cur ^ 1, tt + 1);
      asm volatile("s_waitcnt vmcnt(16)" ::: "memory");  // tile tt landed
    } else {
      asm volatile("s_waitcnt vmcnt(0)" ::: "memory");
    }
    __builtin_amdgcn_sched_barrier(0);

    int kv0 = tt * 32;
    const unsigned short* Kb = &lds[wave][cur][0];
    const unsigned short* Vb = &lds[wave][cur][4096];

    // S^T = K Q^T (A=K row=kv=l31, B=Q col=q=l31); log2 domain
    f32x16 sf;
#pragma unroll
    for (int r = 0; r < 16; ++r) sf[r] = 0.f;
#pragma unroll
    for (int kb = 0; kb < 8; ++kb) {
      int c = (2 * kb + l5) ^ (l31 & 7);
      bf16x8 kf = *reinterpret_cast<const bf16x8*>(Kb + (l31 * 16 + c) * 8);
      sf = __builtin_amdgcn_mfma_f32_32x32x16_bf16(kf, qf[kb], sf, 0, 0, 0);
    }
    if (tt == nt - 1) {  // diagonal tile: causal mask
#pragma unroll
      for (int r = 0; r < 16; ++r) {
        int kv_abs = kv0 + (r & 3) + 8 * (r >> 2) + 4 * l5;
        if (kv_abs > q_abs) sf[r] = -1e30f;
      }
    }
    float pm = -1e30f;
#pragma unroll
    for (int r = 0; r < 16; ++r) pm = fmaxf(pm, sf[r]);
    pm = fmaxf(pm, __shfl_xor(pm, 32));
    float nm = fmaxf(m_r, pm);
    float alpha = exp2f(m_r - nm);
    m_r = nm;
    float ls = 0.f;
#pragma unroll
    for (int r = 0; r < 16; ++r) {
      float pv = exp2f(sf[r] - nm);
      sf[r] = pv;
      ls += pv;
    }
    l_r = l_r * alpha + ls + __shfl_xor(ls, 32);
#pragma unroll
    for (int nf = 0; nf < 4; ++nf)
#pragma unroll
      for (int r = 0; r < 16; ++r) OT[nf][r] *= alpha;

    // P^T B-frags via cvt_pk + shfl_xor(32) (v8-verified recipe)
    bf16x8 pf[2];
#pragma unroll
    for (int ks = 0; ks < 2; ++ks) {
      const int m0 = 8 * ks;
      unsigned A0, A1, B0, B1;
      asm("v_cvt_pk_bf16_f32 %0, %1, %2" : "=v"(A0) : "v"(sf[m0 + 0]), "v"(sf[m0 + 1]));
      asm("v_cvt_pk_bf16_f32 %0, %1, %2" : "=v"(A1) : "v"(sf[m0 + 2]), "v"(sf[m0 + 3]));
      asm("v_cvt_pk_bf16_f32 %0, %1, %2" : "=v"(B0) : "v"(sf[m0 + 4]), "v"(sf[m0 + 5]));
      asm("v_cvt_pk_bf16_f32 %0, %1, %2" : "=v"(B1) : "v"(sf[m0 + 6]), "v"(sf[m0 + 7]));
      unsigned rA0 = (unsigned)__shfl_xor((int)A0, 32);
      unsigned rA1 = (unsigned)__shfl_xor((int)A1, 32);
      unsigned rB0 = (unsigned)__shfl_xor((int)B0, 32);
      unsigned rB1 = (unsigned)__shfl_xor((int)B1, 32);
      union { unsigned u[4]; bf16x8 v; } pk;
      pk.u[0] = l5 ? rB0 : A0;
      pk.u[1] = l5 ? rB1 : A1;
      pk.u[2] = l5 ? B0 : rA0;
      pk.u[3] = l5 ? B1 : rA1;
      pf[ks] = pk.v;
    }

    // O^T += V^T P^T (A=V^T row=d, B=P^T col=q)
#pragma unroll
    for (int ks = 0; ks < 2; ++ks) {
#pragma unroll
      for (int nf = 0; nf < 4; ++nf) {
        int row = nf * 32 + l31;
        int c = (2 * ks + l5) ^ (row & 3);
        bf16x8 vf = *reinterpret_cast<const bf16x8*>(Vb + (row * 4 + c) * 8);
        OT[nf] = __builtin_amdgcn_mfma_f32_32x32x16_bf16(vf, pf[ks], OT[nf], 0, 0, 0);
      }
    }
  }

  // ---- wave-private transpose via own LDS region + coalesced store ----
  {
    unsigned short* Tb = &lds[wave][0][0];  // 32 x 136 bf16 = 8.5 KB (free now)
    float inv = 1.0f / l_r;
#pragma unroll
    for (int nf = 0; nf < 4; ++nf)
#pragma unroll
      for (int r = 0; r < 16; ++r) {
        int d = nf * 32 + (r & 3) + 8 * (r >> 2) + 4 * l5;
        Tb[l31 * 136 + d] = f2b(OT[nf][r] * inv);
      }
    asm volatile("s_waitcnt lgkmcnt(0)" ::: "memory");
    __builtin_amdgcn_sched_barrier(0);
#pragma unroll
    for (int i = 0; i < 8; ++i) {
      int ch = i * 64 + l;
      int row = ch >> 4, c = ch & 15;
      bf16x8 v = *reinterpret_cast<const bf16x8*>(Tb + row * 136 + c * 8);
      *reinterpret_cast<bf16x8*>(
          o + (size_t)(q0w + row) * DMODEL + h * HDIM + c * 8) = v;
    }
  }
}

extern "C" void kernel_launch(void* const* d_in, const int* in_sizes, int n_in,
                              void* d_out, int out_size, void* d_ws, size_t ws_size,
                              hipStream_t stream) {
  const float* hs = (const float*)d_in[0];
  const float* Wq = (const float*)d_in[1];
  const float* Wk = (const float*)d_in[2];
  const float* Wv = (const float*)d_in[3];
  const float* Wo = (const float*)d_in[4];

  char* ws = (char*)d_ws;
  const size_t MB = 1024 * 1024;
  unsigned short* hs_b = (unsigned short*)(ws + 0 * MB);  // reused as vt later
  unsigned short* Wq_b = (unsigned short*)(ws + 8 * MB);
  unsigned short* Wk_b = (unsigned short*)(ws + 16 * MB);
  unsigned short* Wv_b = (unsigned short*)(ws + 24 * MB);
  unsigned short* Wo_b = (unsigned short*)(ws + 32 * MB);
  unsigned short* qb = (unsigned short*)(ws + 40 * MB);
  unsigned short* kb = (unsigned short*)(ws + 48 * MB);
  unsigned short* vb = (unsigned short*)(ws + 56 * MB);
  unsigned short* ab = (unsigned short*)(ws + 64 * MB);
  float* cs = (float*)(ws + 72 * MB);
  float* sn = (float*)(ws + 72 * MB + 512 * 1024);
  unsigned short* vtb = hs_b;  // V^T [h][d][s]; hs_b dead after QKV GEMM

  cvt5_f32_bf16_k<<<(5 * 1024 * 1024) / 256, 256, 0, stream>>>(
      hs, Wq, Wk, Wv, Wo, hs_b, Wq_b, Wk_b, Wv_b, Wo_b);

  rope_table_k<<<(S_LEN * 64) / 256, 256, 0, stream>>>(cs, sn);

  gemm_8ph_k<256, false><<<dim3(64, 1, 3), 512, 0, stream>>>(
      hs_b, Wq_b, Wk_b, Wv_b, qb, kb, vb, 2048, 2048, 2048);

  transpose_bf16_k<<<dim3(32, 32), 256, 0, stream>>>(vb, vtb);

  rope_apply_k<<<(S_LEN * NHEADS * 64) / 256, 256, 0, stream>>>(qb, kb, cs, sn);

  flash_attn_k<<<dim3(256), 256, 0, stream>>>(qb, kb, vtb, ab);

  gemm_8ph_k<128, true><<<dim3(128, 1, 1), 512, 0, stream>>>(
      ab, Wo_b, Wo_b, Wo_b, d_out, d_out, d_out, 2048, 2048, 2048);
}

// Round 12
// 206.184 us; speedup vs baseline: 1.2226x; 1.2226x over previous
//
#include <hip/hip_runtime.h>
#include <hip/hip_bf16.h>
#include <math.h>

#define S_LEN 2048
#define DMODEL 2048
#define NHEADS 16
#define HDIM 128

typedef __bf16 bf16x8 __attribute__((ext_vector_type(8)));
typedef float f32x4 __attribute__((ext_vector_type(4)));
typedef float f32x16 __attribute__((ext_vector_type(16)));

__device__ __forceinline__ unsigned short f2b(float f) {
  union { float f; unsigned u; } c; c.f = f;
  unsigned r = (c.u + 0x7fffu + ((c.u >> 16) & 1u)) >> 16;
  return (unsigned short)r;
}
__device__ __forceinline__ float b2f(unsigned short b) {
  union { unsigned u; float f; } c; c.u = ((unsigned)b) << 16;
  return c.f;
}

__device__ __forceinline__ void gload_lds16(const unsigned short* g, unsigned short* l) {
  __builtin_amdgcn_global_load_lds(
      (__attribute__((address_space(1))) void*)(void*)g,
      (__attribute__((address_space(3))) void*)(void*)l, 16, 0, 0);
}

// ---------------- fused fp32 -> bf16 conversion (5 tensors, one launch) ----
__global__ void cvt5_f32_bf16_k(const float* __restrict__ s0,
                                const float* __restrict__ s1,
                                const float* __restrict__ s2,
                                const float* __restrict__ s3,
                                const float* __restrict__ s4,
                                unsigned short* __restrict__ d0,
                                unsigned short* __restrict__ d1,
                                unsigned short* __restrict__ d2,
                                unsigned short* __restrict__ d3,
                                unsigned short* __restrict__ d4) {
  int gi = blockIdx.x * blockDim.x + threadIdx.x;
  int seg = gi >> 20;
  int i = (gi & 0xFFFFF) * 4;
  const float* src = (seg == 0) ? s0 : (seg == 1) ? s1 : (seg == 2) ? s2
                     : (seg == 3) ? s3 : s4;
  unsigned short* dst = (seg == 0) ? d0 : (seg == 1) ? d1 : (seg == 2) ? d2
                        : (seg == 3) ? d3 : d4;
  float4 v = *reinterpret_cast<const float4*>(src + i);
  ushort4 o;
  o.x = f2b(v.x); o.y = f2b(v.y); o.z = f2b(v.z); o.w = f2b(v.w);
  *reinterpret_cast<ushort4*>(dst + i) = o;
}

// ---------------- f32 split-K reduce: out = a + b ----------------
__global__ void addf2_k(const float* __restrict__ a, const float* __restrict__ b,
                        float* __restrict__ out) {
  int i = (blockIdx.x * blockDim.x + threadIdx.x) * 4;
  float4 x = *reinterpret_cast<const float4*>(a + i);
  float4 y = *reinterpret_cast<const float4*>(b + i);
  x.x += y.x; x.y += y.y; x.z += y.z; x.w += y.w;
  *reinterpret_cast<float4*>(out + i) = x;
}

// ---------------- RoPE cos/sin table ----------------
__global__ void rope_table_k(float* __restrict__ cs, float* __restrict__ sn) {
  int idx = blockIdx.x * blockDim.x + threadIdx.x;  // S_LEN * 64
  int s = idx >> 6, i = idx & 63;
  float inv = powf(10000.0f, -(float)(2 * i) / 128.0f);
  float a = (float)s * inv;
  cs[idx] = cosf(a);
  sn[idx] = sinf(a);
}

// ---------------- RoPE apply (in-place on q,k bf16) ----------------
// q additionally scaled by sm*log2(e): softmax runs in log2 domain.
__global__ void rope_apply_k(unsigned short* __restrict__ q,
                             unsigned short* __restrict__ k,
                             const float* __restrict__ cs,
                             const float* __restrict__ sn) {
  const float SC = 0.08838834764831845f * 1.4426950408889634f;  // sm * log2e
  int idx = blockIdx.x * blockDim.x + threadIdx.x;  // S*H*64
  int i = idx & 63;
  int h = (idx >> 6) & (NHEADS - 1);
  int s = idx >> 10;
  size_t base = (size_t)s * DMODEL + h * HDIM;
  float c = cs[s * 64 + i], sv = sn[s * 64 + i];
  float qc = c * SC, qs = sv * SC;
  float q1 = b2f(q[base + i]), q2 = b2f(q[base + i + 64]);
  q[base + i]      = f2b(q1 * qc - q2 * qs);
  q[base + i + 64] = f2b(q2 * qc + q1 * qs);
  float k1 = b2f(k[base + i]), k2 = b2f(k[base + i + 64]);
  k[base + i]      = f2b(k1 * c - k2 * sv);
  k[base + i + 64] = f2b(k2 * c + k1 * sv);
}

// ---------------- bf16 2048x2048 transpose ----------------
__global__ __launch_bounds__(256) void transpose_bf16_k(
    const unsigned short* __restrict__ in, unsigned short* __restrict__ out) {
  __shared__ unsigned short tile[64][72];
  int bx = blockIdx.x, by = blockIdx.y;
  int t = threadIdx.x;
#pragma unroll
  for (int i = 0; i < 2; ++i) {
    int ch = i * 256 + t;
    int r = ch >> 3, c8 = ch & 7;
    bf16x8 v = *reinterpret_cast<const bf16x8*>(
        in + (size_t)(by * 64 + r) * DMODEL + bx * 64 + c8 * 8);
    *reinterpret_cast<bf16x8*>(&tile[r][c8 * 8]) = v;
  }
  __syncthreads();
#pragma unroll
  for (int i = 0; i < 2; ++i) {
    int ch = i * 256 + t;
    int c = ch >> 3, r8 = ch & 7;
    union { bf16x8 v; unsigned short u[8]; } w;
#pragma unroll
    for (int j = 0; j < 8; ++j) w.u[j] = tile[r8 * 8 + j][c];
    *reinterpret_cast<bf16x8*>(
        out + (size_t)(bx * 64 + c) * S_LEN + by * 64 + r8 * 8) = w.v;
  }
}

// ============ 8-phase 256-wide NT GEMM ============
// Kl = K-loop length (elements), Kstr = row stride, aoffz = per-z A offset
// (split-K support: z selects A+z*aoffz, B-z pointer, C-z pointer).

#define MIDBAR_SEQ()                                      \
  do {                                                    \
    asm volatile("" ::: "memory");                        \
    __builtin_amdgcn_s_barrier();                         \
    asm volatile("s_waitcnt lgkmcnt(0)" ::: "memory");    \
    __builtin_amdgcn_sched_barrier(0);                    \
    __builtin_amdgcn_s_setprio(1);                        \
  } while (0)

#define ENDBAR_SEQ()                                      \
  do {                                                    \
    __builtin_amdgcn_s_setprio(0);                        \
    asm volatile("" ::: "memory");                        \
    __builtin_amdgcn_s_barrier();                         \
    asm volatile("" ::: "memory");                        \
  } while (0)

#define READA(QM)                                                              \
  do {                                                                         \
    _Pragma("unroll") for (int j = 0; j < MQ; ++j)                             \
    _Pragma("unroll") for (int kk = 0; kk < 2; ++kk) {                         \
      int row = wm * (BM / 2) + ((QM) * MQ + j) * 16 + li;                     \
      int c = (kk * 4 + g) ^ (li & 7);                                         \
      af[j][kk] = *reinterpret_cast<const bf16x8*>(&As[cur][row * 64 + c * 8]);\
    }                                                                          \
  } while (0)

#define READB(BF, QN)                                                          \
  do {                                                                         \
    _Pragma("unroll") for (int jn = 0; jn < 2; ++jn)                           \
    _Pragma("unroll") for (int kk = 0; kk < 2; ++kk) {                         \
      int row = wn * 64 + ((QN) * 2 + jn) * 16 + li;                           \
      int c = (kk * 4 + g) ^ (li & 7);                                         \
      BF[jn][kk] = *reinterpret_cast<const bf16x8*>(&Bs[cur][row * 64 + c * 8]);\
    }                                                                          \
  } while (0)

#define QUAD(QM, QN, BF)                                                       \
  do {                                                                         \
    _Pragma("unroll") for (int j = 0; j < MQ; ++j)                             \
    _Pragma("unroll") for (int jn = 0; jn < 2; ++jn)                           \
    _Pragma("unroll") for (int kk = 0; kk < 2; ++kk)                           \
      acc[(QM) * MQ + j][(QN) * 2 + jn] =                                      \
          __builtin_amdgcn_mfma_f32_16x16x32_bf16(                             \
              af[j][kk], BF[jn][kk], acc[(QM) * MQ + j][(QN) * 2 + jn], 0, 0, 0);\
  } while (0)

template <int BM, bool OUT_F32>
__global__ __launch_bounds__(512, 2) void gemm_8ph_k(
    const unsigned short* __restrict__ A, const unsigned short* __restrict__ B0p,
    const unsigned short* __restrict__ B1p, const unsigned short* __restrict__ B2p,
    void* __restrict__ C0, void* __restrict__ C1, void* __restrict__ C2,
    int M, int N, int Kl, int Kstr, int aoffz) {
  constexpr int MQ = BM / 64;
  constexpr int MR = BM / 32;

  __shared__ unsigned short As[2][BM * 64];
  __shared__ unsigned short Bs[2][256 * 64];

  const unsigned short* Ap = A + (size_t)blockIdx.z * aoffz;
  const unsigned short* Bp = (blockIdx.z == 0) ? B0p : (blockIdx.z == 1) ? B1p : B2p;
  void* Cout = (blockIdx.z == 0) ? C0 : (blockIdx.z == 1) ? C1 : C2;

  int nwg = gridDim.x, bid = blockIdx.x;
  int wg = (bid & 7) * (nwg >> 3) + (bid >> 3);
  int ntn = N >> 8;
  int tm = wg / ntn, tn = wg % ntn;
  int m0 = tm * BM, n0 = tn << 8;

  const int tid = threadIdx.x;
  const int wave = tid >> 6, lane = tid & 63;
  const int g = lane >> 4, li = lane & 15;
  const int wm = wave >> 2, wn = wave & 3;

  auto stageB = [&](int buf, int tt, int qn) {
#pragma unroll
    for (int i = 0; i < 2; ++i) {
      int j = i * 512 + tid;
      int piece = j >> 8, rowin = (j >> 3) & 31, c = j & 7;
      int row = piece * 64 + qn * 32 + rowin;
      gload_lds16(Bp + (size_t)(n0 + row) * Kstr + tt * 64 + ((c ^ (row & 7)) * 8),
                  &Bs[buf][row * 64 + c * 8]);
    }
  };
  auto stageA = [&](int buf, int tt, int qm) {
#pragma unroll
    for (int i = 0; i < BM / 128; ++i) {
      int j = i * 512 + tid;
      int piece = j / (2 * BM);
      int rowin = (j >> 3) & (BM / 4 - 1);
      int c = j & 7;
      int row = piece * (BM / 2) + qm * (BM / 4) + rowin;
      gload_lds16(Ap + (size_t)(m0 + row) * Kstr + tt * 64 + ((c ^ (row & 7)) * 8),
                  &As[buf][row * 64 + c * 8]);
    }
  };

  f32x4 acc[MR][4];
#pragma unroll
  for (int i = 0; i < MR; ++i)
#pragma unroll
    for (int j = 0; j < 4; ++j) acc[i][j] = (f32x4){0.f, 0.f, 0.f, 0.f};

  const int nK = Kl >> 6;

  stageB(0, 0, 0); stageA(0, 0, 0); stageB(0, 0, 1); stageA(0, 0, 1);
  stageB(1, 1, 0); stageA(1, 1, 0); stageB(1, 1, 1); stageA(1, 1, 1);
  if constexpr (BM == 256) asm volatile("s_waitcnt vmcnt(8)" ::: "memory");
  else                     asm volatile("s_waitcnt vmcnt(6)" ::: "memory");
  asm volatile("" ::: "memory");
  __builtin_amdgcn_s_barrier();
  asm volatile("" ::: "memory");

  for (int t = 0; t < nK; ++t) {
    int cur = t & 1;
    bool pf = (t + 2 < nK);
    bf16x8 af[MQ][2], bf0[2][2], bf1[2][2];
    READA(0);
    READB(bf0, 0);
    MIDBAR_SEQ();
    QUAD(0, 0, bf0);
    ENDBAR_SEQ();
    READB(bf1, 1);
    if (pf) { stageB(cur, t + 2, 0); stageA(cur, t + 2, 0); }
    MIDBAR_SEQ();
    QUAD(0, 1, bf1);
    ENDBAR_SEQ();
    READA(1);
    if (pf) stageB(cur, t + 2, 1);
    MIDBAR_SEQ();
    QUAD(1, 1, bf1);
    ENDBAR_SEQ();
    if (pf) {
      stageA(cur, t + 2, 1);
      if constexpr (BM == 256) asm volatile("s_waitcnt vmcnt(8)" ::: "memory");
      else                     asm volatile("s_waitcnt vmcnt(6)" ::: "memory");
    } else {
      asm volatile("s_waitcnt vmcnt(0)" ::: "memory");
    }
    MIDBAR_SEQ();
    QUAD(1, 0, bf0);
    ENDBAR_SEQ();
  }

#pragma unroll
  for (int m = 0; m < MR; ++m) {
#pragma unroll
    for (int n = 0; n < 4; ++n) {
      int row = m0 + wm * (BM / 2) + m * 16 + g * 4;
      int col = n0 + wn * 64 + n * 16 + li;
#pragma unroll
      for (int r = 0; r < 4; ++r) {
        if (OUT_F32)
          reinterpret_cast<float*>(Cout)[(size_t)(row + r) * N + col] = acc[m][n][r];
        else
          reinterpret_cast<unsigned short*>(Cout)[(size_t)(row + r) * N + col] =
              f2b(acc[m][n][r]);
      }
    }
  }
}

#undef MIDBAR_SEQ
#undef ENDBAR_SEQ
#undef READA
#undef READB
#undef QUAD

// ---------------- causal flash attention v8 (r10-verified, 71.6 us) ----------
// 512 blocks LPT, 4 waves = 2 q-halves x 2 kv-parities, swapped 32x32 MFMA,
// in-register softmax (scalar m/l), cvt_pk+shfl P-build, LDS merge+store.
__global__ __launch_bounds__(256) void flash_attn_k(
    const unsigned short* __restrict__ q, const unsigned short* __restrict__ k,
    const unsigned short* __restrict__ vt, unsigned short* __restrict__ o) {
  __shared__ unsigned short Ks[2][2][64 * 128];  // [parity][buf] 64 KB
  __shared__ unsigned short Vs[2][2][128 * 64];  // [parity][buf] 64 KB

  int L = blockIdx.x;
  int xcd = L & 7, j = L >> 3;
  int h = 2 * xcd + (j & 1);
  int qt = (j < 32) ? (31 - (j >> 1)) : ((j - 32) >> 1);  // LPT

  int t = threadIdx.x, wave = t >> 6, l = t & 63;
  int l5 = l >> 5, l31 = l & 31;
  int par = wave >> 1, qh = wave & 1;
  int q0 = qt * 64;
  int q_abs = q0 + qh * 32 + l31;

  const unsigned short* vth = vt + (size_t)h * HDIM * S_LEN;

  auto stage = [&](int buf, int itv) {
#pragma unroll
    for (int p2 = 0; p2 < 2; ++p2) {
      int kv0 = (2 * itv + p2) * 64;
#pragma unroll
      for (int i = 0; i < 4; ++i) {
        int ch = i * 256 + t;
        int row = ch >> 4, c = ch & 15;
        gload_lds16(k + (size_t)(kv0 + row) * DMODEL + h * HDIM + ((c ^ (row & 7)) * 8),
                    &Ks[p2][buf][ch * 8]);
      }
#pragma unroll
      for (int i = 0; i < 4; ++i) {
        int ch = i * 256 + t;
        int row = ch >> 3, c = ch & 7;
        gload_lds16(vth + (size_t)row * S_LEN + kv0 + ((c ^ (row & 7)) * 8),
                    &Vs[p2][buf][ch * 8]);
      }
    }
  };

  bf16x8 qf[8];
#pragma unroll
  for (int kb = 0; kb < 8; ++kb)
    qf[kb] = *reinterpret_cast<const bf16x8*>(
        q + (size_t)q_abs * DMODEL + h * HDIM + kb * 16 + l5 * 8);

  f32x16 OT[4];
#pragma unroll
  for (int nf = 0; nf < 4; ++nf)
#pragma unroll
    for (int r = 0; r < 16; ++r) OT[nf][r] = 0.f;
  float m_r = -1e30f, l_r = 0.f;

  int nIter = (qt >> 1) + 1;
  stage(0, 0);

  for (int it = 0; it < nIter; ++it) {
    int cur = it & 1;
    if (it + 1 < nIter) {
      stage(cur ^ 1, it + 1);
      asm volatile("s_waitcnt vmcnt(16)" ::: "memory");
    } else {
      asm volatile("s_waitcnt vmcnt(0)" ::: "memory");
    }
    __builtin_amdgcn_s_barrier();
    asm volatile("" ::: "memory");

    int myt = 2 * it + par;
    if (myt <= qt) {
      int kv0 = myt * 64;
      f32x16 sf[2];
#pragma unroll
      for (int kvs = 0; kvs < 2; ++kvs)
#pragma unroll
        for (int r = 0; r < 16; ++r) sf[kvs][r] = 0.f;
#pragma unroll
      for (int kb = 0; kb < 8; ++kb) {
#pragma unroll
        for (int kvs = 0; kvs < 2; ++kvs) {
          int row = kvs * 32 + l31;
          int c = (2 * kb + l5) ^ (row & 7);
          bf16x8 kf = *reinterpret_cast<const bf16x8*>(&Ks[par][cur][row * 128 + c * 8]);
          sf[kvs] = __builtin_amdgcn_mfma_f32_32x32x16_bf16(kf, qf[kb], sf[kvs], 0, 0, 0);
        }
      }
      if (myt == qt) {
#pragma unroll
        for (int kvs = 0; kvs < 2; ++kvs)
#pragma unroll
          for (int r = 0; r < 16; ++r) {
            int kv_abs = kv0 + kvs * 32 + (r & 3) + 8 * (r >> 2) + 4 * l5;
            if (kv_abs > q_abs) sf[kvs][r] = -1e30f;
          }
      }
      float pm = -1e30f;
#pragma unroll
      for (int kvs = 0; kvs < 2; ++kvs)
#pragma unroll
        for (int r = 0; r < 16; ++r) pm = fmaxf(pm, sf[kvs][r]);
      pm = fmaxf(pm, __shfl_xor(pm, 32));
      float nm = fmaxf(m_r, pm);
      float alpha = exp2f(m_r - nm);
      m_r = nm;
      float ls = 0.f;
#pragma unroll
      for (int kvs = 0; kvs < 2; ++kvs)
#pragma unroll
        for (int r = 0; r < 16; ++r) {
          float pv = exp2f(sf[kvs][r] - nm);
          sf[kvs][r] = pv;
          ls += pv;
        }
      l_r = l_r * alpha + ls + __shfl_xor(ls, 32);
#pragma unroll
      for (int nf = 0; nf < 4; ++nf)
#pragma unroll
        for (int r = 0; r < 16; ++r) OT[nf][r] *= alpha;

      bf16x8 pf[4];
#pragma unroll
      for (int ks = 0; ks < 4; ++ks) {
        const int kvs = ks >> 1;
        const int m0 = 8 * (ks & 1);
        unsigned A0, A1, B0, B1;
        asm("v_cvt_pk_bf16_f32 %0, %1, %2" : "=v"(A0) : "v"(sf[kvs][m0 + 0]), "v"(sf[kvs][m0 + 1]));
        asm("v_cvt_pk_bf16_f32 %0, %1, %2" : "=v"(A1) : "v"(sf[kvs][m0 + 2]), "v"(sf[kvs][m0 + 3]));
        asm("v_cvt_pk_bf16_f32 %0, %1, %2" : "=v"(B0) : "v"(sf[kvs][m0 + 4]), "v"(sf[kvs][m0 + 5]));
        asm("v_cvt_pk_bf16_f32 %0, %1, %2" : "=v"(B1) : "v"(sf[kvs][m0 + 6]), "v"(sf[kvs][m0 + 7]));
        unsigned rA0 = (unsigned)__shfl_xor((int)A0, 32);
        unsigned rA1 = (unsigned)__shfl_xor((int)A1, 32);
        unsigned rB0 = (unsigned)__shfl_xor((int)B0, 32);
        unsigned rB1 = (unsigned)__shfl_xor((int)B1, 32);
        union { unsigned u[4]; bf16x8 v; } pk;
        pk.u[0] = l5 ? rB0 : A0;
        pk.u[1] = l5 ? rB1 : A1;
        pk.u[2] = l5 ? B0 : rA0;
        pk.u[3] = l5 ? B1 : rA1;
        pf[ks] = pk.v;
      }

#pragma unroll
      for (int ks = 0; ks < 4; ++ks) {
#pragma unroll
        for (int nf = 0; nf < 4; ++nf) {
          int row = nf * 32 + l31;
          int c = (2 * ks + l5) ^ (row & 7);
          bf16x8 vf = *reinterpret_cast<const bf16x8*>(&Vs[par][cur][row * 64 + c * 8]);
          OT[nf] = __builtin_amdgcn_mfma_f32_32x32x16_bf16(vf, pf[ks], OT[nf], 0, 0, 0);
        }
      }
    }
    __builtin_amdgcn_s_barrier();
    asm volatile("" ::: "memory");
  }

  // ---- kv-parity merge + transpose + coalesced store ----
  float* MS = (float*)&Ks[0][0][0];
  float* ML = MS + 8192;
  if (par == 1) {
#pragma unroll
    for (int nf = 0; nf < 4; ++nf)
#pragma unroll
      for (int r = 0; r < 16; ++r) {
        int d = nf * 32 + (r & 3) + 8 * (r >> 2) + 4 * l5;
        MS[qh * 4096 + d * 32 + l31] = OT[nf][r];
      }
    if (l < 32) { ML[qh * 64 + l31] = m_r; ML[qh * 64 + 32 + l31] = l_r; }
  }
  __builtin_amdgcn_s_barrier();
  asm volatile("" ::: "memory");
  if (par == 0) {
    float mB = ML[qh * 64 + l31], lB = ML[qh * 64 + 32 + l31];
    float ms = fmaxf(m_r, mB);
    float eA = exp2f(m_r - ms), eB = exp2f(mB - ms);
    float inv = 1.0f / (l_r * eA + lB * eB);
#pragma unroll
    for (int nf = 0; nf < 4; ++nf)
#pragma unroll
      for (int r = 0; r < 16; ++r) {
        int d = nf * 32 + (r & 3) + 8 * (r >> 2) + 4 * l5;
        OT[nf][r] = (OT[nf][r] * eA + MS[qh * 4096 + d * 32 + l31] * eB) * inv;
      }
  }
  __builtin_amdgcn_s_barrier();
  asm volatile("" ::: "memory");
  if (par == 0) {
#pragma unroll
    for (int nf = 0; nf < 4; ++nf)
#pragma unroll
      for (int r = 0; r < 16; ++r) {
        int d = nf * 32 + (r & 3) + 8 * (r >> 2) + 4 * l5;
        MS[qh * 4096 + d * 32 + l31] = OT[nf][r];
      }
  }
  __builtin_amdgcn_s_barrier();
  asm volatile("" ::: "memory");
  {
    int qq = t >> 2;
    int dg = (t & 3) * 32;
    const float* src = MS + (qq >> 5) * 4096 + (qq & 31);
    unsigned pk[16];
#pragma unroll
    for (int i = 0; i < 16; ++i) {
      unsigned lo = f2b(src[(dg + 2 * i) * 32]);
      unsigned hi = f2b(src[(dg + 2 * i + 1) * 32]);
      pk[i] = lo | (hi << 16);
    }
    unsigned short* op = o + (size_t)(q0 + qq) * DMODEL + h * HDIM + dg;
#pragma unroll
    for (int i = 0; i < 4; ++i) {
      uint4 w = make_uint4(pk[4 * i], pk[4 * i + 1], pk[4 * i + 2], pk[4 * i + 3]);
      *reinterpret_cast<uint4*>(op + i * 8) = w;
    }
  }
}

extern "C" void kernel_launch(void* const* d_in, const int* in_sizes, int n_in,
                              void* d_out, int out_size, void* d_ws, size_t ws_size,
                              hipStream_t stream) {
  const float* hs = (const float*)d_in[0];
  const float* Wq = (const float*)d_in[1];
  const float* Wk = (const float*)d_in[2];
  const float* Wv = (const float*)d_in[3];
  const float* Wo = (const float*)d_in[4];

  char* ws = (char*)d_ws;
  const size_t MB = 1024 * 1024;
  unsigned short* hs_b = (unsigned short*)(ws + 0 * MB);  // reused as vt later
  unsigned short* Wq_b = (unsigned short*)(ws + 8 * MB);
  unsigned short* Wk_b = (unsigned short*)(ws + 16 * MB);
  unsigned short* Wv_b = (unsigned short*)(ws + 24 * MB);
  unsigned short* Wo_b = (unsigned short*)(ws + 32 * MB);
  unsigned short* qb = (unsigned short*)(ws + 40 * MB);
  unsigned short* kb = (unsigned short*)(ws + 48 * MB);
  unsigned short* vb = (unsigned short*)(ws + 56 * MB);
  unsigned short* ab = (unsigned short*)(ws + 64 * MB);
  float* cs = (float*)(ws + 72 * MB);
  float* sn = (float*)(ws + 72 * MB + 512 * 1024);
  unsigned short* vtb = hs_b;  // V^T [h][d][s]; hs_b dead after QKV GEMM
  // split-K partials for Wo (dead regions at that point):
  float* P0 = (float*)(ws + 8 * MB);   // Wq_b/Wk_b dead (16 MB)
  float* P1 = (float*)(ws + 40 * MB);  // qb/kb dead (16 MB)

  cvt5_f32_bf16_k<<<(5 * 1024 * 1024) / 256, 256, 0, stream>>>(
      hs, Wq, Wk, Wv, Wo, hs_b, Wq_b, Wk_b, Wv_b, Wo_b);

  rope_table_k<<<(S_LEN * 64) / 256, 256, 0, stream>>>(cs, sn);

  // fused QKV projection: 256x256 tiles, full K
  gemm_8ph_k<256, false><<<dim3(64, 1, 3), 512, 0, stream>>>(
      hs_b, Wq_b, Wk_b, Wv_b, qb, kb, vb, 2048, 2048, 2048, 2048, 0);

  transpose_bf16_k<<<dim3(32, 32), 256, 0, stream>>>(vb, vtb);

  rope_apply_k<<<(S_LEN * NHEADS * 64) / 256, 256, 0, stream>>>(qb, kb, cs, sn);

  flash_attn_k<<<dim3(512), 256, 0, stream>>>(qb, kb, vtb, ab);

  // output projection: split-K=2 -> 256 blocks (all CUs), f32 partials + reduce
  gemm_8ph_k<128, true><<<dim3(128, 1, 2), 512, 0, stream>>>(
      ab, Wo_b, Wo_b + 1024, Wo_b, P0, P1, P0, 2048, 2048, 1024, 2048, 1024);
  addf2_k<<<(2048 * 2048) / 1024, 256, 0, stream>>>(P0, P1, (float*)d_out);
}

// Round 13
// 204.311 us; speedup vs baseline: 1.2338x; 1.0092x over previous
//
#include <hip/hip_runtime.h>
#include <hip/hip_bf16.h>
#include <math.h>

#define S_LEN 2048
#define DMODEL 2048
#define NHEADS 16
#define HDIM 128

typedef __bf16 bf16x8 __attribute__((ext_vector_type(8)));
typedef float f32x4 __attribute__((ext_vector_type(4)));
typedef float f32x16 __attribute__((ext_vector_type(16)));

__device__ __forceinline__ unsigned short f2b(float f) {
  union { float f; unsigned u; } c; c.f = f;
  unsigned r = (c.u + 0x7fffu + ((c.u >> 16) & 1u)) >> 16;
  return (unsigned short)r;
}
__device__ __forceinline__ float b2f(unsigned short b) {
  union { unsigned u; float f; } c; c.u = ((unsigned)b) << 16;
  return c.f;
}

__device__ __forceinline__ void gload_lds16(const unsigned short* g, unsigned short* l) {
  __builtin_amdgcn_global_load_lds(
      (__attribute__((address_space(1))) void*)(void*)g,
      (__attribute__((address_space(3))) void*)(void*)l, 16, 0, 0);
}

// ---------------- fused fp32 -> bf16 conversion (5 tensors, one launch) ----
__global__ void cvt5_f32_bf16_k(const float* __restrict__ s0,
                                const float* __restrict__ s1,
                                const float* __restrict__ s2,
                                const float* __restrict__ s3,
                                const float* __restrict__ s4,
                                unsigned short* __restrict__ d0,
                                unsigned short* __restrict__ d1,
                                unsigned short* __restrict__ d2,
                                unsigned short* __restrict__ d3,
                                unsigned short* __restrict__ d4) {
  int gi = blockIdx.x * blockDim.x + threadIdx.x;
  int seg = gi >> 20;
  int i = (gi & 0xFFFFF) * 4;
  const float* src = (seg == 0) ? s0 : (seg == 1) ? s1 : (seg == 2) ? s2
                     : (seg == 3) ? s3 : s4;
  unsigned short* dst = (seg == 0) ? d0 : (seg == 1) ? d1 : (seg == 2) ? d2
                        : (seg == 3) ? d3 : d4;
  float4 v = *reinterpret_cast<const float4*>(src + i);
  ushort4 o;
  o.x = f2b(v.x); o.y = f2b(v.y); o.z = f2b(v.z); o.w = f2b(v.w);
  *reinterpret_cast<ushort4*>(dst + i) = o;
}

// ---------------- f32 split-K reduce: out = a + b ----------------
__global__ void addf2_k(const float* __restrict__ a, const float* __restrict__ b,
                        float* __restrict__ out) {
  int i = (blockIdx.x * blockDim.x + threadIdx.x) * 4;
  float4 x = *reinterpret_cast<const float4*>(a + i);
  float4 y = *reinterpret_cast<const float4*>(b + i);
  x.x += y.x; x.y += y.y; x.z += y.z; x.w += y.w;
  *reinterpret_cast<float4*>(out + i) = x;
}

// ---------------- RoPE cos/sin table ----------------
__global__ void rope_table_k(float* __restrict__ cs, float* __restrict__ sn) {
  int idx = blockIdx.x * blockDim.x + threadIdx.x;  // S_LEN * 64
  int s = idx >> 6, i = idx & 63;
  float inv = powf(10000.0f, -(float)(2 * i) / 128.0f);
  float a = (float)s * inv;
  cs[idx] = cosf(a);
  sn[idx] = sinf(a);
}

// ---------------- RoPE apply (in-place on q,k bf16) ----------------
// q additionally scaled by sm*log2(e): softmax runs in log2 domain.
__global__ void rope_apply_k(unsigned short* __restrict__ q,
                             unsigned short* __restrict__ k,
                             const float* __restrict__ cs,
                             const float* __restrict__ sn) {
  const float SC = 0.08838834764831845f * 1.4426950408889634f;  // sm * log2e
  int idx = blockIdx.x * blockDim.x + threadIdx.x;  // S*H*64
  int i = idx & 63;
  int h = (idx >> 6) & (NHEADS - 1);
  int s = idx >> 10;
  size_t base = (size_t)s * DMODEL + h * HDIM;
  float c = cs[s * 64 + i], sv = sn[s * 64 + i];
  float qc = c * SC, qs = sv * SC;
  float q1 = b2f(q[base + i]), q2 = b2f(q[base + i + 64]);
  q[base + i]      = f2b(q1 * qc - q2 * qs);
  q[base + i + 64] = f2b(q2 * qc + q1 * qs);
  float k1 = b2f(k[base + i]), k2 = b2f(k[base + i + 64]);
  k[base + i]      = f2b(k1 * c - k2 * sv);
  k[base + i + 64] = f2b(k2 * c + k1 * sv);
}

// ---------------- bf16 2048x2048 transpose ----------------
__global__ __launch_bounds__(256) void transpose_bf16_k(
    const unsigned short* __restrict__ in, unsigned short* __restrict__ out) {
  __shared__ unsigned short tile[64][72];
  int bx = blockIdx.x, by = blockIdx.y;
  int t = threadIdx.x;
#pragma unroll
  for (int i = 0; i < 2; ++i) {
    int ch = i * 256 + t;
    int r = ch >> 3, c8 = ch & 7;
    bf16x8 v = *reinterpret_cast<const bf16x8*>(
        in + (size_t)(by * 64 + r) * DMODEL + bx * 64 + c8 * 8);
    *reinterpret_cast<bf16x8*>(&tile[r][c8 * 8]) = v;
  }
  __syncthreads();
#pragma unroll
  for (int i = 0; i < 2; ++i) {
    int ch = i * 256 + t;
    int c = ch >> 3, r8 = ch & 7;
    union { bf16x8 v; unsigned short u[8]; } w;
#pragma unroll
    for (int j = 0; j < 8; ++j) w.u[j] = tile[r8 * 8 + j][c];
    *reinterpret_cast<bf16x8*>(
        out + (size_t)(bx * 64 + c) * S_LEN + by * 64 + r8 * 8) = w.v;
  }
}

// ============ 8-phase 256-wide NT GEMM ============
// Kl = K-loop length, Kstr = row stride, aoffz = per-z A offset (split-K).

#define MIDBAR_SEQ()                                      \
  do {                                                    \
    asm volatile("" ::: "memory");                        \
    __builtin_amdgcn_s_barrier();                         \
    asm volatile("s_waitcnt lgkmcnt(0)" ::: "memory");    \
    __builtin_amdgcn_sched_barrier(0);                    \
    __builtin_amdgcn_s_setprio(1);                        \
  } while (0)

#define ENDBAR_SEQ()                                      \
  do {                                                    \
    __builtin_amdgcn_s_setprio(0);                        \
    asm volatile("" ::: "memory");                        \
    __builtin_amdgcn_s_barrier();                         \
    asm volatile("" ::: "memory");                        \
  } while (0)

#define READA(QM)                                                              \
  do {                                                                         \
    _Pragma("unroll") for (int j = 0; j < MQ; ++j)                             \
    _Pragma("unroll") for (int kk = 0; kk < 2; ++kk) {                         \
      int row = wm * (BM / 2) + ((QM) * MQ + j) * 16 + li;                     \
      int c = (kk * 4 + g) ^ (li & 7);                                         \
      af[j][kk] = *reinterpret_cast<const bf16x8*>(&As[cur][row * 64 + c * 8]);\
    }                                                                          \
  } while (0)

#define READB(BF, QN)                                                          \
  do {                                                                         \
    _Pragma("unroll") for (int jn = 0; jn < 2; ++jn)                           \
    _Pragma("unroll") for (int kk = 0; kk < 2; ++kk) {                         \
      int row = wn * 64 + ((QN) * 2 + jn) * 16 + li;                           \
      int c = (kk * 4 + g) ^ (li & 7);                                         \
      BF[jn][kk] = *reinterpret_cast<const bf16x8*>(&Bs[cur][row * 64 + c * 8]);\
    }                                                                          \
  } while (0)

#define QUAD(QM, QN, BF)                                                       \
  do {                                                                         \
    _Pragma("unroll") for (int j = 0; j < MQ; ++j)                             \
    _Pragma("unroll") for (int jn = 0; jn < 2; ++jn)                           \
    _Pragma("unroll") for (int kk = 0; kk < 2; ++kk)                           \
      acc[(QM) * MQ + j][(QN) * 2 + jn] =                                      \
          __builtin_amdgcn_mfma_f32_16x16x32_bf16(                             \
              af[j][kk], BF[jn][kk], acc[(QM) * MQ + j][(QN) * 2 + jn], 0, 0, 0);\
  } while (0)

template <int BM, bool OUT_F32>
__global__ __launch_bounds__(512, 2) void gemm_8ph_k(
    const unsigned short* __restrict__ A, const unsigned short* __restrict__ B0p,
    const unsigned short* __restrict__ B1p, const unsigned short* __restrict__ B2p,
    void* __restrict__ C0, void* __restrict__ C1, void* __restrict__ C2,
    int M, int N, int Kl, int Kstr, int aoffz) {
  constexpr int MQ = BM / 64;
  constexpr int MR = BM / 32;

  __shared__ unsigned short As[2][BM * 64];
  __shared__ unsigned short Bs[2][256 * 64];

  const unsigned short* Ap = A + (size_t)blockIdx.z * aoffz;
  const unsigned short* Bp = (blockIdx.z == 0) ? B0p : (blockIdx.z == 1) ? B1p : B2p;
  void* Cout = (blockIdx.z == 0) ? C0 : (blockIdx.z == 1) ? C1 : C2;

  int nwg = gridDim.x, bid = blockIdx.x;
  int wg = (bid & 7) * (nwg >> 3) + (bid >> 3);
  int ntn = N >> 8;
  int tm = wg / ntn, tn = wg % ntn;
  int m0 = tm * BM, n0 = tn << 8;

  const int tid = threadIdx.x;
  const int wave = tid >> 6, lane = tid & 63;
  const int g = lane >> 4, li = lane & 15;
  const int wm = wave >> 2, wn = wave & 3;

  auto stageB = [&](int buf, int tt, int qn) {
#pragma unroll
    for (int i = 0; i < 2; ++i) {
      int j = i * 512 + tid;
      int piece = j >> 8, rowin = (j >> 3) & 31, c = j & 7;
      int row = piece * 64 + qn * 32 + rowin;
      gload_lds16(Bp + (size_t)(n0 + row) * Kstr + tt * 64 + ((c ^ (row & 7)) * 8),
                  &Bs[buf][row * 64 + c * 8]);
    }
  };
  auto stageA = [&](int buf, int tt, int qm) {
#pragma unroll
    for (int i = 0; i < BM / 128; ++i) {
      int j = i * 512 + tid;
      int piece = j / (2 * BM);
      int rowin = (j >> 3) & (BM / 4 - 1);
      int c = j & 7;
      int row = piece * (BM / 2) + qm * (BM / 4) + rowin;
      gload_lds16(Ap + (size_t)(m0 + row) * Kstr + tt * 64 + ((c ^ (row & 7)) * 8),
                  &As[buf][row * 64 + c * 8]);
    }
  };

  f32x4 acc[MR][4];
#pragma unroll
  for (int i = 0; i < MR; ++i)
#pragma unroll
    for (int j = 0; j < 4; ++j) acc[i][j] = (f32x4){0.f, 0.f, 0.f, 0.f};

  const int nK = Kl >> 6;

  stageB(0, 0, 0); stageA(0, 0, 0); stageB(0, 0, 1); stageA(0, 0, 1);
  stageB(1, 1, 0); stageA(1, 1, 0); stageB(1, 1, 1); stageA(1, 1, 1);
  if constexpr (BM == 256) asm volatile("s_waitcnt vmcnt(8)" ::: "memory");
  else                     asm volatile("s_waitcnt vmcnt(6)" ::: "memory");
  asm volatile("" ::: "memory");
  __builtin_amdgcn_s_barrier();
  asm volatile("" ::: "memory");

  for (int t = 0; t < nK; ++t) {
    int cur = t & 1;
    bool pf = (t + 2 < nK);
    bf16x8 af[MQ][2], bf0[2][2], bf1[2][2];
    READA(0);
    READB(bf0, 0);
    MIDBAR_SEQ();
    QUAD(0, 0, bf0);
    ENDBAR_SEQ();
    READB(bf1, 1);
    if (pf) { stageB(cur, t + 2, 0); stageA(cur, t + 2, 0); }
    MIDBAR_SEQ();
    QUAD(0, 1, bf1);
    ENDBAR_SEQ();
    READA(1);
    if (pf) stageB(cur, t + 2, 1);
    MIDBAR_SEQ();
    QUAD(1, 1, bf1);
    ENDBAR_SEQ();
    if (pf) {
      stageA(cur, t + 2, 1);
      if constexpr (BM == 256) asm volatile("s_waitcnt vmcnt(8)" ::: "memory");
      else                     asm volatile("s_waitcnt vmcnt(6)" ::: "memory");
    } else {
      asm volatile("s_waitcnt vmcnt(0)" ::: "memory");
    }
    MIDBAR_SEQ();
    QUAD(1, 0, bf0);
    ENDBAR_SEQ();
  }

#pragma unroll
  for (int m = 0; m < MR; ++m) {
#pragma unroll
    for (int n = 0; n < 4; ++n) {
      int row = m0 + wm * (BM / 2) + m * 16 + g * 4;
      int col = n0 + wn * 64 + n * 16 + li;
#pragma unroll
      for (int r = 0; r < 4; ++r) {
        if (OUT_F32)
          reinterpret_cast<float*>(Cout)[(size_t)(row + r) * N + col] = acc[m][n][r];
        else
          reinterpret_cast<unsigned short*>(Cout)[(size_t)(row + r) * N + col] =
              f2b(acc[m][n][r]);
      }
    }
  }
}

#undef MIDBAR_SEQ
#undef ENDBAR_SEQ
#undef READA
#undef READB
#undef QUAD

// ---------------- causal flash attention v10: 32-row kv tiles, 64 KB LDS ----
// v8 skeleton (512 blocks LPT, 4 waves = 2 q-halves x 2 kv-parities, swapped
// 32x32 MFMA, in-register softmax, cvt_pk+shfl P-build, LDS merge+store) with
// kv-tile halved to 32 rows/parity: LDS 128->64 KB => 2 blocks/CU co-resident
// (2 waves/SIMD) to hide the per-tile serial chain. Per-iter chain also
// halves (8+8 MFMA); iter count doubles (qt+1); both parities active every
// iteration.
__global__ __launch_bounds__(256) void flash_attn_k(
    const unsigned short* __restrict__ q, const unsigned short* __restrict__ k,
    const unsigned short* __restrict__ vt, unsigned short* __restrict__ o) {
  __shared__ unsigned short Ks[2][2][32 * 128];  // [parity][buf] 32 KB
  __shared__ unsigned short Vs[2][2][128 * 32];  // [parity][buf] 32 KB

  int L = blockIdx.x;
  int xcd = L & 7, j = L >> 3;
  int h = 2 * xcd + (j & 1);
  int qt = (j < 32) ? (31 - (j >> 1)) : ((j - 32) >> 1);  // LPT

  int t = threadIdx.x, wave = t >> 6, l = t & 63;
  int l5 = l >> 5, l31 = l & 31;
  int par = wave >> 1, qh = wave & 1;
  int q0 = qt * 64;
  int q_abs = q0 + qh * 32 + l31;

  const unsigned short* vth = vt + (size_t)h * HDIM * S_LEN;

  // stage kv rows [64*it + 32*p2, +32) for both parities: 8 loads/thread
  auto stage = [&](int buf, int it) {
#pragma unroll
    for (int p2 = 0; p2 < 2; ++p2) {
      int kv0 = it * 64 + p2 * 32;
#pragma unroll
      for (int i = 0; i < 2; ++i) {  // K: 32 rows x 16 chunks
        int ch = i * 256 + t;
        int row = ch >> 4, c = ch & 15;
        gload_lds16(k + (size_t)(kv0 + row) * DMODEL + h * HDIM + ((c ^ (row & 7)) * 8),
                    &Ks[p2][buf][ch * 8]);
      }
#pragma unroll
      for (int i = 0; i < 2; ++i) {  // V^T: 128 rows x 4 chunks
        int ch = i * 256 + t;
        int row = ch >> 2, c = ch & 3;
        gload_lds16(vth + (size_t)row * S_LEN + kv0 + ((c ^ (row & 3)) * 8),
                    &Vs[p2][buf][ch * 8]);
      }
    }
  };

  bf16x8 qf[8];
#pragma unroll
  for (int kb = 0; kb < 8; ++kb)
    qf[kb] = *reinterpret_cast<const bf16x8*>(
        q + (size_t)q_abs * DMODEL + h * HDIM + kb * 16 + l5 * 8);

  f32x16 OT[4];
#pragma unroll
  for (int nf = 0; nf < 4; ++nf)
#pragma unroll
    for (int r = 0; r < 16; ++r) OT[nf][r] = 0.f;
  float m_r = -1e30f, l_r = 0.f;

  int nIter = qt + 1;
  stage(0, 0);

  for (int it = 0; it < nIter; ++it) {
    int cur = it & 1;
    if (it + 1 < nIter) {
      stage(cur ^ 1, it + 1);
      asm volatile("s_waitcnt vmcnt(8)" ::: "memory");
    } else {
      asm volatile("s_waitcnt vmcnt(0)" ::: "memory");
    }
    __builtin_amdgcn_s_barrier();
    asm volatile("" ::: "memory");

    int kv0 = it * 64 + par * 32;
    // S^T = K Q^T (A=K row=kv=l31, B=Q col=q=l31); log2 domain
    f32x16 sf;
#pragma unroll
    for (int r = 0; r < 16; ++r) sf[r] = 0.f;
#pragma unroll
    for (int kb = 0; kb < 8; ++kb) {
      int c = (2 * kb + l5) ^ (l31 & 7);
      bf16x8 kf = *reinterpret_cast<const bf16x8*>(&Ks[par][cur][(l31 * 16 + c) * 8]);
      sf = __builtin_amdgcn_mfma_f32_32x32x16_bf16(kf, qf[kb], sf, 0, 0, 0);
    }
    if (it == qt) {  // diagonal 64-row block: causal mask
#pragma unroll
      for (int r = 0; r < 16; ++r) {
        int kv_abs = kv0 + (r & 3) + 8 * (r >> 2) + 4 * l5;
        if (kv_abs > q_abs) sf[r] = -1e30f;
      }
    }
    float pm = -1e30f;
#pragma unroll
    for (int r = 0; r < 16; ++r) pm = fmaxf(pm, sf[r]);
    pm = fmaxf(pm, __shfl_xor(pm, 32));
    float nm = fmaxf(m_r, pm);
    float alpha = exp2f(m_r - nm);
    m_r = nm;
    float ls = 0.f;
#pragma unroll
    for (int r = 0; r < 16; ++r) {
      float pv = exp2f(sf[r] - nm);
      sf[r] = pv;
      ls += pv;
    }
    l_r = l_r * alpha + ls + __shfl_xor(ls, 32);
#pragma unroll
    for (int nf = 0; nf < 4; ++nf)
#pragma unroll
      for (int r = 0; r < 16; ++r) OT[nf][r] *= alpha;

    // P^T B-frags via cvt_pk + shfl_xor(32) (verified recipe)
    bf16x8 pf[2];
#pragma unroll
    for (int ks = 0; ks < 2; ++ks) {
      const int m0 = 8 * ks;
      unsigned A0, A1, B0, B1;
      asm("v_cvt_pk_bf16_f32 %0, %1, %2" : "=v"(A0) : "v"(sf[m0 + 0]), "v"(sf[m0 + 1]));
      asm("v_cvt_pk_bf16_f32 %0, %1, %2" : "=v"(A1) : "v"(sf[m0 + 2]), "v"(sf[m0 + 3]));
      asm("v_cvt_pk_bf16_f32 %0, %1, %2" : "=v"(B0) : "v"(sf[m0 + 4]), "v"(sf[m0 + 5]));
      asm("v_cvt_pk_bf16_f32 %0, %1, %2" : "=v"(B1) : "v"(sf[m0 + 6]), "v"(sf[m0 + 7]));
      unsigned rA0 = (unsigned)__shfl_xor((int)A0, 32);
      unsigned rA1 = (unsigned)__shfl_xor((int)A1, 32);
      unsigned rB0 = (unsigned)__shfl_xor((int)B0, 32);
      unsigned rB1 = (unsigned)__shfl_xor((int)B1, 32);
      union { unsigned u[4]; bf16x8 v; } pk;
      pk.u[0] = l5 ? rB0 : A0;
      pk.u[1] = l5 ? rB1 : A1;
      pk.u[2] = l5 ? B0 : rA0;
      pk.u[3] = l5 ? B1 : rA1;
      pf[ks] = pk.v;
    }

    // O^T += V^T P^T (A=V^T row=d, B=P^T col=q)
#pragma unroll
    for (int ks = 0; ks < 2; ++ks) {
#pragma unroll
      for (int nf = 0; nf < 4; ++nf) {
        int row = nf * 32 + l31;
        int c = (2 * ks + l5) ^ (row & 3);
        bf16x8 vf = *reinterpret_cast<const bf16x8*>(&Vs[par][cur][(row * 4 + c) * 8]);
        OT[nf] = __builtin_amdgcn_mfma_f32_32x32x16_bf16(vf, pf[ks], OT[nf], 0, 0, 0);
      }
    }
    __builtin_amdgcn_s_barrier();
    asm volatile("" ::: "memory");
  }

  // ---- kv-parity merge + transpose + coalesced store (v8-verified) ----
  float* MS = (float*)&Ks[0][0][0];  // 2 x 4096 f32 = 32 KB (all of Ks)
  float* ML = MS + 8192;             // into Vs
  if (par == 1) {
#pragma unroll
    for (int nf = 0; nf < 4; ++nf)
#pragma unroll
      for (int r = 0; r < 16; ++r) {
        int d = nf * 32 + (r & 3) + 8 * (r >> 2) + 4 * l5;
        MS[qh * 4096 + d * 32 + l31] = OT[nf][r];
      }
    if (l < 32) { ML[qh * 64 + l31] = m_r; ML[qh * 64 + 32 + l31] = l_r; }
  }
  __builtin_amdgcn_s_barrier();
  asm volatile("" ::: "memory");
  if (par == 0) {
    float mB = ML[qh * 64 + l31], lB = ML[qh * 64 + 32 + l31];
    float ms = fmaxf(m_r, mB);
    float eA = exp2f(m_r - ms), eB = exp2f(mB - ms);
    float inv = 1.0f / (l_r * eA + lB * eB);
#pragma unroll
    for (int nf = 0; nf < 4; ++nf)
#pragma unroll
      for (int r = 0; r < 16; ++r) {
        int d = nf * 32 + (r & 3) + 8 * (r >> 2) + 4 * l5;
        OT[nf][r] = (OT[nf][r] * eA + MS[qh * 4096 + d * 32 + l31] * eB) * inv;
      }
  }
  __builtin_amdgcn_s_barrier();
  asm volatile("" ::: "memory");
  if (par == 0) {
#pragma unroll
    for (int nf = 0; nf < 4; ++nf)
#pragma unroll
      for (int r = 0; r < 16; ++r) {
        int d = nf * 32 + (r & 3) + 8 * (r >> 2) + 4 * l5;
        MS[qh * 4096 + d * 32 + l31] = OT[nf][r];
      }
  }
  __builtin_amdgcn_s_barrier();
  asm volatile("" ::: "memory");
  {
    int qq = t >> 2;
    int dg = (t & 3) * 32;
    const float* src = MS + (qq >> 5) * 4096 + (qq & 31);
    unsigned pk[16];
#pragma unroll
    for (int i = 0; i < 16; ++i) {
      unsigned lo = f2b(src[(dg + 2 * i) * 32]);
      unsigned hi = f2b(src[(dg + 2 * i + 1) * 32]);
      pk[i] = lo | (hi << 16);
    }
    unsigned short* op = o + (size_t)(q0 + qq) * DMODEL + h * HDIM + dg;
#pragma unroll
    for (int i = 0; i < 4; ++i) {
      uint4 w = make_uint4(pk[4 * i], pk[4 * i + 1], pk[4 * i + 2], pk[4 * i + 3]);
      *reinterpret_cast<uint4*>(op + i * 8) = w;
    }
  }
}

extern "C" void kernel_launch(void* const* d_in, const int* in_sizes, int n_in,
                              void* d_out, int out_size, void* d_ws, size_t ws_size,
                              hipStream_t stream) {
  const float* hs = (const float*)d_in[0];
  const float* Wq = (const float*)d_in[1];
  const float* Wk = (const float*)d_in[2];
  const float* Wv = (const float*)d_in[3];
  const float* Wo = (const float*)d_in[4];

  char* ws = (char*)d_ws;
  const size_t MB = 1024 * 1024;
  unsigned short* hs_b = (unsigned short*)(ws + 0 * MB);  // reused as vt later
  unsigned short* Wq_b = (unsigned short*)(ws + 8 * MB);
  unsigned short* Wk_b = (unsigned short*)(ws + 16 * MB);
  unsigned short* Wv_b = (unsigned short*)(ws + 24 * MB);
  unsigned short* Wo_b = (unsigned short*)(ws + 32 * MB);
  unsigned short* qb = (unsigned short*)(ws + 40 * MB);
  unsigned short* kb = (unsigned short*)(ws + 48 * MB);
  unsigned short* vb = (unsigned short*)(ws + 56 * MB);
  unsigned short* ab = (unsigned short*)(ws + 64 * MB);
  float* cs = (float*)(ws + 72 * MB);
  float* sn = (float*)(ws + 72 * MB + 512 * 1024);
  unsigned short* vtb = hs_b;  // V^T [h][d][s]; hs_b dead after QKV GEMM
  float* P0 = (float*)(ws + 8 * MB);   // Wq_b/Wk_b dead at Wo time
  float* P1 = (float*)(ws + 40 * MB);  // qb/kb dead at Wo time

  cvt5_f32_bf16_k<<<(5 * 1024 * 1024) / 256, 256, 0, stream>>>(
      hs, Wq, Wk, Wv, Wo, hs_b, Wq_b, Wk_b, Wv_b, Wo_b);

  rope_table_k<<<(S_LEN * 64) / 256, 256, 0, stream>>>(cs, sn);

  gemm_8ph_k<256, false><<<dim3(64, 1, 3), 512, 0, stream>>>(
      hs_b, Wq_b, Wk_b, Wv_b, qb, kb, vb, 2048, 2048, 2048, 2048, 0);

  transpose_bf16_k<<<dim3(32, 32), 256, 0, stream>>>(vb, vtb);

  rope_apply_k<<<(S_LEN * NHEADS * 64) / 256, 256, 0, stream>>>(qb, kb, cs, sn);

  flash_attn_k<<<dim3(512), 256, 0, stream>>>(qb, kb, vtb, ab);

  gemm_8ph_k<128, true><<<dim3(128, 1, 2), 512, 0, stream>>>(
      ab, Wo_b, Wo_b + 1024, Wo_b, P0, P1, P0, 2048, 2048, 1024, 2048, 1024);
  addf2_k<<<(2048 * 2048) / 1024, 256, 0, stream>>>(P0, P1, (float*)d_out);
}

// Round 14
// 202.753 us; speedup vs baseline: 1.2433x; 1.0077x over previous
//
#include <hip/hip_runtime.h>
#include <hip/hip_bf16.h>
#include <math.h>

#define S_LEN 2048
#define DMODEL 2048
#define NHEADS 16
#define HDIM 128

typedef __bf16 bf16x8 __attribute__((ext_vector_type(8)));
typedef float f32x4 __attribute__((ext_vector_type(4)));
typedef float f32x16 __attribute__((ext_vector_type(16)));

__device__ __forceinline__ unsigned short f2b(float f) {
  union { float f; unsigned u; } c; c.f = f;
  unsigned r = (c.u + 0x7fffu + ((c.u >> 16) & 1u)) >> 16;
  return (unsigned short)r;
}
__device__ __forceinline__ float b2f(unsigned short b) {
  union { unsigned u; float f; } c; c.u = ((unsigned)b) << 16;
  return c.f;
}

__device__ __forceinline__ void gload_lds16(const unsigned short* g, unsigned short* l) {
  __builtin_amdgcn_global_load_lds(
      (__attribute__((address_space(1))) void*)(void*)g,
      (__attribute__((address_space(3))) void*)(void*)l, 16, 0, 0);
}

// ---------------- fused fp32 -> bf16 conversion (5 tensors, one launch) ----
__global__ void cvt5_f32_bf16_k(const float* __restrict__ s0,
                                const float* __restrict__ s1,
                                const float* __restrict__ s2,
                                const float* __restrict__ s3,
                                const float* __restrict__ s4,
                                unsigned short* __restrict__ d0,
                                unsigned short* __restrict__ d1,
                                unsigned short* __restrict__ d2,
                                unsigned short* __restrict__ d3,
                                unsigned short* __restrict__ d4) {
  int gi = blockIdx.x * blockDim.x + threadIdx.x;
  int seg = gi >> 20;
  int i = (gi & 0xFFFFF) * 4;
  const float* src = (seg == 0) ? s0 : (seg == 1) ? s1 : (seg == 2) ? s2
                     : (seg == 3) ? s3 : s4;
  unsigned short* dst = (seg == 0) ? d0 : (seg == 1) ? d1 : (seg == 2) ? d2
                        : (seg == 3) ? d3 : d4;
  float4 v = *reinterpret_cast<const float4*>(src + i);
  ushort4 o;
  o.x = f2b(v.x); o.y = f2b(v.y); o.z = f2b(v.z); o.w = f2b(v.w);
  *reinterpret_cast<ushort4*>(dst + i) = o;
}

// ---------------- f32 split-K reduce: out = a + b ----------------
__global__ void addf2_k(const float* __restrict__ a, const float* __restrict__ b,
                        float* __restrict__ out) {
  int i = (blockIdx.x * blockDim.x + threadIdx.x) * 4;
  float4 x = *reinterpret_cast<const float4*>(a + i);
  float4 y = *reinterpret_cast<const float4*>(b + i);
  x.x += y.x; x.y += y.y; x.z += y.z; x.w += y.w;
  *reinterpret_cast<float4*>(out + i) = x;
}

// ---------------- RoPE cos/sin table ----------------
__global__ void rope_table_k(float* __restrict__ cs, float* __restrict__ sn) {
  int idx = blockIdx.x * blockDim.x + threadIdx.x;  // S_LEN * 64
  int s = idx >> 6, i = idx & 63;
  float inv = powf(10000.0f, -(float)(2 * i) / 128.0f);
  float a = (float)s * inv;
  cs[idx] = cosf(a);
  sn[idx] = sinf(a);
}

// ---------------- RoPE apply (in-place on q,k bf16) ----------------
// q additionally scaled by sm*log2(e): softmax runs in log2 domain.
__global__ void rope_apply_k(unsigned short* __restrict__ q,
                             unsigned short* __restrict__ k,
                             const float* __restrict__ cs,
                             const float* __restrict__ sn) {
  const float SC = 0.08838834764831845f * 1.4426950408889634f;  // sm * log2e
  int idx = blockIdx.x * blockDim.x + threadIdx.x;  // S*H*64
  int i = idx & 63;
  int h = (idx >> 6) & (NHEADS - 1);
  int s = idx >> 10;
  size_t base = (size_t)s * DMODEL + h * HDIM;
  float c = cs[s * 64 + i], sv = sn[s * 64 + i];
  float qc = c * SC, qs = sv * SC;
  float q1 = b2f(q[base + i]), q2 = b2f(q[base + i + 64]);
  q[base + i]      = f2b(q1 * qc - q2 * qs);
  q[base + i + 64] = f2b(q2 * qc + q1 * qs);
  float k1 = b2f(k[base + i]), k2 = b2f(k[base + i + 64]);
  k[base + i]      = f2b(k1 * c - k2 * sv);
  k[base + i + 64] = f2b(k2 * c + k1 * sv);
}

// ---------------- bf16 2048x2048 transpose ----------------
__global__ __launch_bounds__(256) void transpose_bf16_k(
    const unsigned short* __restrict__ in, unsigned short* __restrict__ out) {
  __shared__ unsigned short tile[64][72];
  int bx = blockIdx.x, by = blockIdx.y;
  int t = threadIdx.x;
#pragma unroll
  for (int i = 0; i < 2; ++i) {
    int ch = i * 256 + t;
    int r = ch >> 3, c8 = ch & 7;
    bf16x8 v = *reinterpret_cast<const bf16x8*>(
        in + (size_t)(by * 64 + r) * DMODEL + bx * 64 + c8 * 8);
    *reinterpret_cast<bf16x8*>(&tile[r][c8 * 8]) = v;
  }
  __syncthreads();
#pragma unroll
  for (int i = 0; i < 2; ++i) {
    int ch = i * 256 + t;
    int c = ch >> 3, r8 = ch & 7;
    union { bf16x8 v; unsigned short u[8]; } w;
#pragma unroll
    for (int j = 0; j < 8; ++j) w.u[j] = tile[r8 * 8 + j][c];
    *reinterpret_cast<bf16x8*>(
        out + (size_t)(bx * 64 + c) * S_LEN + by * 64 + r8 * 8) = w.v;
  }
}

// ============ 8-phase 256-wide NT GEMM ============
// Kl = K-loop length, Kstr = row stride, aoffz = per-z A offset (split-K).
// Tile->XCD map (r14): XCD = bid%8 (hw: (bid + nwg*z)%8 with nwg%8==0).
//   tm = bid>>3  -> each XCD streams all A-panels, but per-K-step working
//                   set is ~350 KB -> L2-resident streaming reuse.
//   tn = ((bid&7) + 3z)&7 -> each XCD touches ONE B-panel per z
//                   (3 MB QKV / 1 MB Wo-split) -> B L2-resident.
// Bijective per z; requires N==2048 (ntn==8).

#define MIDBAR_SEQ()                                      \
  do {                                                    \
    asm volatile("" ::: "memory");                        \
    __builtin_amdgcn_s_barrier();                         \
    asm volatile("s_waitcnt lgkmcnt(0)" ::: "memory");    \
    __builtin_amdgcn_sched_barrier(0);                    \
    __builtin_amdgcn_s_setprio(1);                        \
  } while (0)

#define ENDBAR_SEQ()                                      \
  do {                                                    \
    __builtin_amdgcn_s_setprio(0);                        \
    asm volatile("" ::: "memory");                        \
    __builtin_amdgcn_s_barrier();                         \
    asm volatile("" ::: "memory");                        \
  } while (0)

#define READA(QM)                                                              \
  do {                                                                         \
    _Pragma("unroll") for (int j = 0; j < MQ; ++j)                             \
    _Pragma("unroll") for (int kk = 0; kk < 2; ++kk) {                         \
      int row = wm * (BM / 2) + ((QM) * MQ + j) * 16 + li;                     \
      int c = (kk * 4 + g) ^ (li & 7);                                         \
      af[j][kk] = *reinterpret_cast<const bf16x8*>(&As[cur][row * 64 + c * 8]);\
    }                                                                          \
  } while (0)

#define READB(BF, QN)                                                          \
  do {                                                                         \
    _Pragma("unroll") for (int jn = 0; jn < 2; ++jn)                           \
    _Pragma("unroll") for (int kk = 0; kk < 2; ++kk) {                         \
      int row = wn * 64 + ((QN) * 2 + jn) * 16 + li;                           \
      int c = (kk * 4 + g) ^ (li & 7);                                         \
      BF[jn][kk] = *reinterpret_cast<const bf16x8*>(&Bs[cur][row * 64 + c * 8]);\
    }                                                                          \
  } while (0)

#define QUAD(QM, QN, BF)                                                       \
  do {                                                                         \
    _Pragma("unroll") for (int j = 0; j < MQ; ++j)                             \
    _Pragma("unroll") for (int jn = 0; jn < 2; ++jn)                           \
    _Pragma("unroll") for (int kk = 0; kk < 2; ++kk)                           \
      acc[(QM) * MQ + j][(QN) * 2 + jn] =                                      \
          __builtin_amdgcn_mfma_f32_16x16x32_bf16(                             \
              af[j][kk], BF[jn][kk], acc[(QM) * MQ + j][(QN) * 2 + jn], 0, 0, 0);\
  } while (0)

template <int BM, bool OUT_F32>
__global__ __launch_bounds__(512, 2) void gemm_8ph_k(
    const unsigned short* __restrict__ A, const unsigned short* __restrict__ B0p,
    const unsigned short* __restrict__ B1p, const unsigned short* __restrict__ B2p,
    void* __restrict__ C0, void* __restrict__ C1, void* __restrict__ C2,
    int M, int N, int Kl, int Kstr, int aoffz) {
  constexpr int MQ = BM / 64;
  constexpr int MR = BM / 32;

  __shared__ unsigned short As[2][BM * 64];
  __shared__ unsigned short Bs[2][256 * 64];

  const unsigned short* Ap = A + (size_t)blockIdx.z * aoffz;
  const unsigned short* Bp = (blockIdx.z == 0) ? B0p : (blockIdx.z == 1) ? B1p : B2p;
  void* Cout = (blockIdx.z == 0) ? C0 : (blockIdx.z == 1) ? C1 : C2;

  int bid = blockIdx.x;
  // B-panel L2-locality mapping (see header comment)
  int tm = bid >> 3;
  int tn = ((bid & 7) + 3 * (int)blockIdx.z) & 7;
  int m0 = tm * BM, n0 = tn << 8;

  const int tid = threadIdx.x;
  const int wave = tid >> 6, lane = tid & 63;
  const int g = lane >> 4, li = lane & 15;
  const int wm = wave >> 2, wn = wave & 3;

  auto stageB = [&](int buf, int tt, int qn) {
#pragma unroll
    for (int i = 0; i < 2; ++i) {
      int j = i * 512 + tid;
      int piece = j >> 8, rowin = (j >> 3) & 31, c = j & 7;
      int row = piece * 64 + qn * 32 + rowin;
      gload_lds16(Bp + (size_t)(n0 + row) * Kstr + tt * 64 + ((c ^ (row & 7)) * 8),
                  &Bs[buf][row * 64 + c * 8]);
    }
  };
  auto stageA = [&](int buf, int tt, int qm) {
#pragma unroll
    for (int i = 0; i < BM / 128; ++i) {
      int j = i * 512 + tid;
      int piece = j / (2 * BM);
      int rowin = (j >> 3) & (BM / 4 - 1);
      int c = j & 7;
      int row = piece * (BM / 2) + qm * (BM / 4) + rowin;
      gload_lds16(Ap + (size_t)(m0 + row) * Kstr + tt * 64 + ((c ^ (row & 7)) * 8),
                  &As[buf][row * 64 + c * 8]);
    }
  };

  f32x4 acc[MR][4];
#pragma unroll
  for (int i = 0; i < MR; ++i)
#pragma unroll
    for (int j = 0; j < 4; ++j) acc[i][j] = (f32x4){0.f, 0.f, 0.f, 0.f};

  const int nK = Kl >> 6;

  stageB(0, 0, 0); stageA(0, 0, 0); stageB(0, 0, 1); stageA(0, 0, 1);
  stageB(1, 1, 0); stageA(1, 1, 0); stageB(1, 1, 1); stageA(1, 1, 1);
  if constexpr (BM == 256) asm volatile("s_waitcnt vmcnt(8)" ::: "memory");
  else                     asm volatile("s_waitcnt vmcnt(6)" ::: "memory");
  asm volatile("" ::: "memory");
  __builtin_amdgcn_s_barrier();
  asm volatile("" ::: "memory");

  for (int t = 0; t < nK; ++t) {
    int cur = t & 1;
    bool pf = (t + 2 < nK);
    bf16x8 af[MQ][2], bf0[2][2], bf1[2][2];
    READA(0);
    READB(bf0, 0);
    MIDBAR_SEQ();
    QUAD(0, 0, bf0);
    ENDBAR_SEQ();
    READB(bf1, 1);
    if (pf) { stageB(cur, t + 2, 0); stageA(cur, t + 2, 0); }
    MIDBAR_SEQ();
    QUAD(0, 1, bf1);
    ENDBAR_SEQ();
    READA(1);
    if (pf) stageB(cur, t + 2, 1);
    MIDBAR_SEQ();
    QUAD(1, 1, bf1);
    ENDBAR_SEQ();
    if (pf) {
      stageA(cur, t + 2, 1);
      if constexpr (BM == 256) asm volatile("s_waitcnt vmcnt(8)" ::: "memory");
      else                     asm volatile("s_waitcnt vmcnt(6)" ::: "memory");
    } else {
      asm volatile("s_waitcnt vmcnt(0)" ::: "memory");
    }
    MIDBAR_SEQ();
    QUAD(1, 0, bf0);
    ENDBAR_SEQ();
  }

#pragma unroll
  for (int m = 0; m < MR; ++m) {
#pragma unroll
    for (int n = 0; n < 4; ++n) {
      int row = m0 + wm * (BM / 2) + m * 16 + g * 4;
      int col = n0 + wn * 64 + n * 16 + li;
#pragma unroll
      for (int r = 0; r < 4; ++r) {
        if (OUT_F32)
          reinterpret_cast<float*>(Cout)[(size_t)(row + r) * N + col] = acc[m][n][r];
        else
          reinterpret_cast<unsigned short*>(Cout)[(size_t)(row + r) * N + col] =
              f2b(acc[m][n][r]);
      }
    }
  }
}

#undef MIDBAR_SEQ
#undef ENDBAR_SEQ
#undef READA
#undef READB
#undef QUAD

// ---------------- causal flash attention v10 (r13, verified) ----------------
__global__ __launch_bounds__(256) void flash_attn_k(
    const unsigned short* __restrict__ q, const unsigned short* __restrict__ k,
    const unsigned short* __restrict__ vt, unsigned short* __restrict__ o) {
  __shared__ unsigned short Ks[2][2][32 * 128];  // [parity][buf] 32 KB
  __shared__ unsigned short Vs[2][2][128 * 32];  // [parity][buf] 32 KB

  int L = blockIdx.x;
  int xcd = L & 7, j = L >> 3;
  int h = 2 * xcd + (j & 1);
  int qt = (j < 32) ? (31 - (j >> 1)) : ((j - 32) >> 1);  // LPT

  int t = threadIdx.x, wave = t >> 6, l = t & 63;
  int l5 = l >> 5, l31 = l & 31;
  int par = wave >> 1, qh = wave & 1;
  int q0 = qt * 64;
  int q_abs = q0 + qh * 32 + l31;

  const unsigned short* vth = vt + (size_t)h * HDIM * S_LEN;

  auto stage = [&](int buf, int it) {
#pragma unroll
    for (int p2 = 0; p2 < 2; ++p2) {
      int kv0 = it * 64 + p2 * 32;
#pragma unroll
      for (int i = 0; i < 2; ++i) {
        int ch = i * 256 + t;
        int row = ch >> 4, c = ch & 15;
        gload_lds16(k + (size_t)(kv0 + row) * DMODEL + h * HDIM + ((c ^ (row & 7)) * 8),
                    &Ks[p2][buf][ch * 8]);
      }
#pragma unroll
      for (int i = 0; i < 2; ++i) {
        int ch = i * 256 + t;
        int row = ch >> 2, c = ch & 3;
        gload_lds16(vth + (size_t)row * S_LEN + kv0 + ((c ^ (row & 3)) * 8),
                    &Vs[p2][buf][ch * 8]);
      }
    }
  };

  bf16x8 qf[8];
#pragma unroll
  for (int kb = 0; kb < 8; ++kb)
    qf[kb] = *reinterpret_cast<const bf16x8*>(
        q + (size_t)q_abs * DMODEL + h * HDIM + kb * 16 + l5 * 8);

  f32x16 OT[4];
#pragma unroll
  for (int nf = 0; nf < 4; ++nf)
#pragma unroll
    for (int r = 0; r < 16; ++r) OT[nf][r] = 0.f;
  float m_r = -1e30f, l_r = 0.f;

  int nIter = qt + 1;
  stage(0, 0);

  for (int it = 0; it < nIter; ++it) {
    int cur = it & 1;
    if (it + 1 < nIter) {
      stage(cur ^ 1, it + 1);
      asm volatile("s_waitcnt vmcnt(8)" ::: "memory");
    } else {
      asm volatile("s_waitcnt vmcnt(0)" ::: "memory");
    }
    __builtin_amdgcn_s_barrier();
    asm volatile("" ::: "memory");

    int kv0 = it * 64 + par * 32;
    f32x16 sf;
#pragma unroll
    for (int r = 0; r < 16; ++r) sf[r] = 0.f;
#pragma unroll
    for (int kb = 0; kb < 8; ++kb) {
      int c = (2 * kb + l5) ^ (l31 & 7);
      bf16x8 kf = *reinterpret_cast<const bf16x8*>(&Ks[par][cur][(l31 * 16 + c) * 8]);
      sf = __builtin_amdgcn_mfma_f32_32x32x16_bf16(kf, qf[kb], sf, 0, 0, 0);
    }
    if (it == qt) {
#pragma unroll
      for (int r = 0; r < 16; ++r) {
        int kv_abs = kv0 + (r & 3) + 8 * (r >> 2) + 4 * l5;
        if (kv_abs > q_abs) sf[r] = -1e30f;
      }
    }
    float pm = -1e30f;
#pragma unroll
    for (int r = 0; r < 16; ++r) pm = fmaxf(pm, sf[r]);
    pm = fmaxf(pm, __shfl_xor(pm, 32));
    float nm = fmaxf(m_r, pm);
    float alpha = exp2f(m_r - nm);
    m_r = nm;
    float ls = 0.f;
#pragma unroll
    for (int r = 0; r < 16; ++r) {
      float pv = exp2f(sf[r] - nm);
      sf[r] = pv;
      ls += pv;
    }
    l_r = l_r * alpha + ls + __shfl_xor(ls, 32);
#pragma unroll
    for (int nf = 0; nf < 4; ++nf)
#pragma unroll
      for (int r = 0; r < 16; ++r) OT[nf][r] *= alpha;

    bf16x8 pf[2];
#pragma unroll
    for (int ks = 0; ks < 2; ++ks) {
      const int m0 = 8 * ks;
      unsigned A0, A1, B0, B1;
      asm("v_cvt_pk_bf16_f32 %0, %1, %2" : "=v"(A0) : "v"(sf[m0 + 0]), "v"(sf[m0 + 1]));
      asm("v_cvt_pk_bf16_f32 %0, %1, %2" : "=v"(A1) : "v"(sf[m0 + 2]), "v"(sf[m0 + 3]));
      asm("v_cvt_pk_bf16_f32 %0, %1, %2" : "=v"(B0) : "v"(sf[m0 + 4]), "v"(sf[m0 + 5]));
      asm("v_cvt_pk_bf16_f32 %0, %1, %2" : "=v"(B1) : "v"(sf[m0 + 6]), "v"(sf[m0 + 7]));
      unsigned rA0 = (unsigned)__shfl_xor((int)A0, 32);
      unsigned rA1 = (unsigned)__shfl_xor((int)A1, 32);
      unsigned rB0 = (unsigned)__shfl_xor((int)B0, 32);
      unsigned rB1 = (unsigned)__shfl_xor((int)B1, 32);
      union { unsigned u[4]; bf16x8 v; } pk;
      pk.u[0] = l5 ? rB0 : A0;
      pk.u[1] = l5 ? rB1 : A1;
      pk.u[2] = l5 ? B0 : rA0;
      pk.u[3] = l5 ? B1 : rA1;
      pf[ks] = pk.v;
    }

#pragma unroll
    for (int ks = 0; ks < 2; ++ks) {
#pragma unroll
      for (int nf = 0; nf < 4; ++nf) {
        int row = nf * 32 + l31;
        int c = (2 * ks + l5) ^ (row & 3);
        bf16x8 vf = *reinterpret_cast<const bf16x8*>(&Vs[par][cur][(row * 4 + c) * 8]);
        OT[nf] = __builtin_amdgcn_mfma_f32_32x32x16_bf16(vf, pf[ks], OT[nf], 0, 0, 0);
      }
    }
    __builtin_amdgcn_s_barrier();
    asm volatile("" ::: "memory");
  }

  // ---- kv-parity merge + transpose + coalesced store ----
  float* MS = (float*)&Ks[0][0][0];
  float* ML = MS + 8192;
  if (par == 1) {
#pragma unroll
    for (int nf = 0; nf < 4; ++nf)
#pragma unroll
      for (int r = 0; r < 16; ++r) {
        int d = nf * 32 + (r & 3) + 8 * (r >> 2) + 4 * l5;
        MS[qh * 4096 + d * 32 + l31] = OT[nf][r];
      }
    if (l < 32) { ML[qh * 64 + l31] = m_r; ML[qh * 64 + 32 + l31] = l_r; }
  }
  __builtin_amdgcn_s_barrier();
  asm volatile("" ::: "memory");
  if (par == 0) {
    float mB = ML[qh * 64 + l31], lB = ML[qh * 64 + 32 + l31];
    float ms = fmaxf(m_r, mB);
    float eA = exp2f(m_r - ms), eB = exp2f(mB - ms);
    float inv = 1.0f / (l_r * eA + lB * eB);
#pragma unroll
    for (int nf = 0; nf < 4; ++nf)
#pragma unroll
      for (int r = 0; r < 16; ++r) {
        int d = nf * 32 + (r & 3) + 8 * (r >> 2) + 4 * l5;
        OT[nf][r] = (OT[nf][r] * eA + MS[qh * 4096 + d * 32 + l31] * eB) * inv;
      }
  }
  __builtin_amdgcn_s_barrier();
  asm volatile("" ::: "memory");
  if (par == 0) {
#pragma unroll
    for (int nf = 0; nf < 4; ++nf)
#pragma unroll
      for (int r = 0; r < 16; ++r) {
        int d = nf * 32 + (r & 3) + 8 * (r >> 2) + 4 * l5;
        MS[qh * 4096 + d * 32 + l31] = OT[nf][r];
      }
  }
  __builtin_amdgcn_s_barrier();
  asm volatile("" ::: "memory");
  {
    int qq = t >> 2;
    int dg = (t & 3) * 32;
    const float* src = MS + (qq >> 5) * 4096 + (qq & 31);
    unsigned pk[16];
#pragma unroll
    for (int i = 0; i < 16; ++i) {
      unsigned lo = f2b(src[(dg + 2 * i) * 32]);
      unsigned hi = f2b(src[(dg + 2 * i + 1) * 32]);
      pk[i] = lo | (hi << 16);
    }
    unsigned short* op = o + (size_t)(q0 + qq) * DMODEL + h * HDIM + dg;
#pragma unroll
    for (int i = 0; i < 4; ++i) {
      uint4 w = make_uint4(pk[4 * i], pk[4 * i + 1], pk[4 * i + 2], pk[4 * i + 3]);
      *reinterpret_cast<uint4*>(op + i * 8) = w;
    }
  }
}

extern "C" void kernel_launch(void* const* d_in, const int* in_sizes, int n_in,
                              void* d_out, int out_size, void* d_ws, size_t ws_size,
                              hipStream_t stream) {
  const float* hs = (const float*)d_in[0];
  const float* Wq = (const float*)d_in[1];
  const float* Wk = (const float*)d_in[2];
  const float* Wv = (const float*)d_in[3];
  const float* Wo = (const float*)d_in[4];

  char* ws = (char*)d_ws;
  const size_t MB = 1024 * 1024;
  unsigned short* hs_b = (unsigned short*)(ws + 0 * MB);  // reused as vt later
  unsigned short* Wq_b = (unsigned short*)(ws + 8 * MB);
  unsigned short* Wk_b = (unsigned short*)(ws + 16 * MB);
  unsigned short* Wv_b = (unsigned short*)(ws + 24 * MB);
  unsigned short* Wo_b = (unsigned short*)(ws + 32 * MB);
  unsigned short* qb = (unsigned short*)(ws + 40 * MB);
  unsigned short* kb = (unsigned short*)(ws + 48 * MB);
  unsigned short* vb = (unsigned short*)(ws + 56 * MB);
  unsigned short* ab = (unsigned short*)(ws + 64 * MB);
  float* cs = (float*)(ws + 72 * MB);
  float* sn = (float*)(ws + 72 * MB + 512 * 1024);
  unsigned short* vtb = hs_b;  // V^T [h][d][s]; hs_b dead after QKV GEMM
  float* P0 = (float*)(ws + 8 * MB);   // Wq_b/Wk_b dead at Wo time
  float* P1 = (float*)(ws + 40 * MB);  // qb/kb dead at Wo time

  cvt5_f32_bf16_k<<<(5 * 1024 * 1024) / 256, 256, 0, stream>>>(
      hs, Wq, Wk, Wv, Wo, hs_b, Wq_b, Wk_b, Wv_b, Wo_b);

  rope_table_k<<<(S_LEN * 64) / 256, 256, 0, stream>>>(cs, sn);

  gemm_8ph_k<256, false><<<dim3(64, 1, 3), 512, 0, stream>>>(
      hs_b, Wq_b, Wk_b, Wv_b, qb, kb, vb, 2048, 2048, 2048, 2048, 0);

  transpose_bf16_k<<<dim3(32, 32), 256, 0, stream>>>(vb, vtb);

  rope_apply_k<<<(S_LEN * NHEADS * 64) / 256, 256, 0, stream>>>(qb, kb, cs, sn);

  flash_attn_k<<<dim3(512), 256, 0, stream>>>(qb, kb, vtb, ab);

  gemm_8ph_k<128, true><<<dim3(128, 1, 2), 512, 0, stream>>>(
      ab, Wo_b, Wo_b + 1024, Wo_b, P0, P1, P0, 2048, 2048, 1024, 2048, 1024);
  addf2_k<<<(2048 * 2048) / 1024, 256, 0, stream>>>(P0, P1, (float*)d_out);
}

// Round 15
// 198.160 us; speedup vs baseline: 1.2721x; 1.0232x over previous
//
#include <hip/hip_runtime.h>
#include <hip/hip_bf16.h>
#include <math.h>

#define S_LEN 2048
#define DMODEL 2048
#define NHEADS 16
#define HDIM 128

typedef __bf16 bf16x8 __attribute__((ext_vector_type(8)));
typedef float f32x4 __attribute__((ext_vector_type(4)));
typedef float f32x16 __attribute__((ext_vector_type(16)));

__device__ __forceinline__ unsigned short f2b(float f) {
  union { float f; unsigned u; } c; c.f = f;
  unsigned r = (c.u + 0x7fffu + ((c.u >> 16) & 1u)) >> 16;
  return (unsigned short)r;
}
__device__ __forceinline__ float b2f(unsigned short b) {
  union { unsigned u; float f; } c; c.u = ((unsigned)b) << 16;
  return c.f;
}

__device__ __forceinline__ void gload_lds16(const unsigned short* g, unsigned short* l) {
  __builtin_amdgcn_global_load_lds(
      (__attribute__((address_space(1))) void*)(void*)g,
      (__attribute__((address_space(3))) void*)(void*)l, 16, 0, 0);
}

// ---------------- fused fp32 -> bf16 conversion (5 tensors, one launch) ----
__global__ void cvt5_f32_bf16_k(const float* __restrict__ s0,
                                const float* __restrict__ s1,
                                const float* __restrict__ s2,
                                const float* __restrict__ s3,
                                const float* __restrict__ s4,
                                unsigned short* __restrict__ d0,
                                unsigned short* __restrict__ d1,
                                unsigned short* __restrict__ d2,
                                unsigned short* __restrict__ d3,
                                unsigned short* __restrict__ d4) {
  int gi = blockIdx.x * blockDim.x + threadIdx.x;
  int seg = gi >> 20;
  int i = (gi & 0xFFFFF) * 4;
  const float* src = (seg == 0) ? s0 : (seg == 1) ? s1 : (seg == 2) ? s2
                     : (seg == 3) ? s3 : s4;
  unsigned short* dst = (seg == 0) ? d0 : (seg == 1) ? d1 : (seg == 2) ? d2
                        : (seg == 3) ? d3 : d4;
  float4 v = *reinterpret_cast<const float4*>(src + i);
  ushort4 o;
  o.x = f2b(v.x); o.y = f2b(v.y); o.z = f2b(v.z); o.w = f2b(v.w);
  *reinterpret_cast<ushort4*>(dst + i) = o;
}

// ---------------- f32 split-K reduce: out = a + b ----------------
__global__ void addf2_k(const float* __restrict__ a, const float* __restrict__ b,
                        float* __restrict__ out) {
  int i = (blockIdx.x * blockDim.x + threadIdx.x) * 4;
  float4 x = *reinterpret_cast<const float4*>(a + i);
  float4 y = *reinterpret_cast<const float4*>(b + i);
  x.x += y.x; x.y += y.y; x.z += y.z; x.w += y.w;
  *reinterpret_cast<float4*>(out + i) = x;
}

// ---------------- RoPE cos/sin table ----------------
__global__ void rope_table_k(float* __restrict__ cs, float* __restrict__ sn) {
  int idx = blockIdx.x * blockDim.x + threadIdx.x;  // S_LEN * 64
  int s = idx >> 6, i = idx & 63;
  float inv = powf(10000.0f, -(float)(2 * i) / 128.0f);
  float a = (float)s * inv;
  cs[idx] = cosf(a);
  sn[idx] = sinf(a);
}

// ---------------- RoPE apply (in-place on q,k bf16) ----------------
// q additionally scaled by sm*log2(e): softmax runs in log2 domain.
__global__ void rope_apply_k(unsigned short* __restrict__ q,
                             unsigned short* __restrict__ k,
                             const float* __restrict__ cs,
                             const float* __restrict__ sn) {
  const float SC = 0.08838834764831845f * 1.4426950408889634f;  // sm * log2e
  int idx = blockIdx.x * blockDim.x + threadIdx.x;  // S*H*64
  int i = idx & 63;
  int h = (idx >> 6) & (NHEADS - 1);
  int s = idx >> 10;
  size_t base = (size_t)s * DMODEL + h * HDIM;
  float c = cs[s * 64 + i], sv = sn[s * 64 + i];
  float qc = c * SC, qs = sv * SC;
  float q1 = b2f(q[base + i]), q2 = b2f(q[base + i + 64]);
  q[base + i]      = f2b(q1 * qc - q2 * qs);
  q[base + i + 64] = f2b(q2 * qc + q1 * qs);
  float k1 = b2f(k[base + i]), k2 = b2f(k[base + i + 64]);
  k[base + i]      = f2b(k1 * c - k2 * sv);
  k[base + i + 64] = f2b(k2 * c + k1 * sv);
}

// ---------------- bf16 2048x2048 transpose ----------------
__global__ __launch_bounds__(256) void transpose_bf16_k(
    const unsigned short* __restrict__ in, unsigned short* __restrict__ out) {
  __shared__ unsigned short tile[64][72];
  int bx = blockIdx.x, by = blockIdx.y;
  int t = threadIdx.x;
#pragma unroll
  for (int i = 0; i < 2; ++i) {
    int ch = i * 256 + t;
    int r = ch >> 3, c8 = ch & 7;
    bf16x8 v = *reinterpret_cast<const bf16x8*>(
        in + (size_t)(by * 64 + r) * DMODEL + bx * 64 + c8 * 8);
    *reinterpret_cast<bf16x8*>(&tile[r][c8 * 8]) = v;
  }
  __syncthreads();
#pragma unroll
  for (int i = 0; i < 2; ++i) {
    int ch = i * 256 + t;
    int c = ch >> 3, r8 = ch & 7;
    union { bf16x8 v; unsigned short u[8]; } w;
#pragma unroll
    for (int j = 0; j < 8; ++j) w.u[j] = tile[r8 * 8 + j][c];
    *reinterpret_cast<bf16x8*>(
        out + (size_t)(bx * 64 + c) * S_LEN + by * 64 + r8 * 8) = w.v;
  }
}

// ============ 8-phase 256-wide NT GEMM ============
// r15: MIDBAR matches the m201-verified phase sequence exactly: barrier +
// lgkmcnt(0) + setprio. The previous sched_barrier(0) per phase was an
// m141-class order-pinning regression (only needed for inline-asm ds_reads,
// rule #18; ours are compiler-tracked C++ loads).

#define MIDBAR_SEQ()                                      \
  do {                                                    \
    asm volatile("" ::: "memory");                        \
    __builtin_amdgcn_s_barrier();                         \
    asm volatile("s_waitcnt lgkmcnt(0)" ::: "memory");    \
    __builtin_amdgcn_s_setprio(1);                        \
  } while (0)

#define ENDBAR_SEQ()                                      \
  do {                                                    \
    __builtin_amdgcn_s_setprio(0);                        \
    asm volatile("" ::: "memory");                        \
    __builtin_amdgcn_s_barrier();                         \
    asm volatile("" ::: "memory");                        \
  } while (0)

#define READA(QM)                                                              \
  do {                                                                         \
    _Pragma("unroll") for (int j = 0; j < MQ; ++j)                             \
    _Pragma("unroll") for (int kk = 0; kk < 2; ++kk) {                         \
      int row = wm * (BM / 2) + ((QM) * MQ + j) * 16 + li;                     \
      int c = (kk * 4 + g) ^ (li & 7);                                         \
      af[j][kk] = *reinterpret_cast<const bf16x8*>(&As[cur][row * 64 + c * 8]);\
    }                                                                          \
  } while (0)

#define READB(BF, QN)                                                          \
  do {                                                                         \
    _Pragma("unroll") for (int jn = 0; jn < 2; ++jn)                           \
    _Pragma("unroll") for (int kk = 0; kk < 2; ++kk) {                         \
      int row = wn * 64 + ((QN) * 2 + jn) * 16 + li;                           \
      int c = (kk * 4 + g) ^ (li & 7);                                         \
      BF[jn][kk] = *reinterpret_cast<const bf16x8*>(&Bs[cur][row * 64 + c * 8]);\
    }                                                                          \
  } while (0)

#define QUAD(QM, QN, BF)                                                       \
  do {                                                                         \
    _Pragma("unroll") for (int j = 0; j < MQ; ++j)                             \
    _Pragma("unroll") for (int jn = 0; jn < 2; ++jn)                           \
    _Pragma("unroll") for (int kk = 0; kk < 2; ++kk)                           \
      acc[(QM) * MQ + j][(QN) * 2 + jn] =                                      \
          __builtin_amdgcn_mfma_f32_16x16x32_bf16(                             \
              af[j][kk], BF[jn][kk], acc[(QM) * MQ + j][(QN) * 2 + jn], 0, 0, 0);\
  } while (0)

template <int BM, bool OUT_F32>
__global__ __launch_bounds__(512, 2) void gemm_8ph_k(
    const unsigned short* __restrict__ A, const unsigned short* __restrict__ B0p,
    const unsigned short* __restrict__ B1p, const unsigned short* __restrict__ B2p,
    void* __restrict__ C0, void* __restrict__ C1, void* __restrict__ C2,
    int M, int N, int Kl, int Kstr, int aoffz) {
  constexpr int MQ = BM / 64;
  constexpr int MR = BM / 32;

  __shared__ unsigned short As[2][BM * 64];
  __shared__ unsigned short Bs[2][256 * 64];

  const unsigned short* Ap = A + (size_t)blockIdx.z * aoffz;
  const unsigned short* Bp = (blockIdx.z == 0) ? B0p : (blockIdx.z == 1) ? B1p : B2p;
  void* Cout = (blockIdx.z == 0) ? C0 : (blockIdx.z == 1) ? C1 : C2;

  int bid = blockIdx.x;
  // B-panel L2-locality mapping (r14-verified: FETCH 102->45 MB)
  int tm = bid >> 3;
  int tn = ((bid & 7) + 3 * (int)blockIdx.z) & 7;
  int m0 = tm * BM, n0 = tn << 8;

  const int tid = threadIdx.x;
  const int wave = tid >> 6, lane = tid & 63;
  const int g = lane >> 4, li = lane & 15;
  const int wm = wave >> 2, wn = wave & 3;

  auto stageB = [&](int buf, int tt, int qn) {
#pragma unroll
    for (int i = 0; i < 2; ++i) {
      int j = i * 512 + tid;
      int piece = j >> 8, rowin = (j >> 3) & 31, c = j & 7;
      int row = piece * 64 + qn * 32 + rowin;
      gload_lds16(Bp + (size_t)(n0 + row) * Kstr + tt * 64 + ((c ^ (row & 7)) * 8),
                  &Bs[buf][row * 64 + c * 8]);
    }
  };
  auto stageA = [&](int buf, int tt, int qm) {
#pragma unroll
    for (int i = 0; i < BM / 128; ++i) {
      int j = i * 512 + tid;
      int piece = j / (2 * BM);
      int rowin = (j >> 3) & (BM / 4 - 1);
      int c = j & 7;
      int row = piece * (BM / 2) + qm * (BM / 4) + rowin;
      gload_lds16(Ap + (size_t)(m0 + row) * Kstr + tt * 64 + ((c ^ (row & 7)) * 8),
                  &As[buf][row * 64 + c * 8]);
    }
  };

  f32x4 acc[MR][4];
#pragma unroll
  for (int i = 0; i < MR; ++i)
#pragma unroll
    for (int j = 0; j < 4; ++j) acc[i][j] = (f32x4){0.f, 0.f, 0.f, 0.f};

  const int nK = Kl >> 6;

  stageB(0, 0, 0); stageA(0, 0, 0); stageB(0, 0, 1); stageA(0, 0, 1);
  stageB(1, 1, 0); stageA(1, 1, 0); stageB(1, 1, 1); stageA(1, 1, 1);
  if constexpr (BM == 256) asm volatile("s_waitcnt vmcnt(8)" ::: "memory");
  else                     asm volatile("s_waitcnt vmcnt(6)" ::: "memory");
  asm volatile("" ::: "memory");
  __builtin_amdgcn_s_barrier();
  asm volatile("" ::: "memory");

  for (int t = 0; t < nK; ++t) {
    int cur = t & 1;
    bool pf = (t + 2 < nK);
    bf16x8 af[MQ][2], bf0[2][2], bf1[2][2];
    READA(0);
    READB(bf0, 0);
    MIDBAR_SEQ();
    QUAD(0, 0, bf0);
    ENDBAR_SEQ();
    READB(bf1, 1);
    if (pf) { stageB(cur, t + 2, 0); stageA(cur, t + 2, 0); }
    MIDBAR_SEQ();
    QUAD(0, 1, bf1);
    ENDBAR_SEQ();
    READA(1);
    if (pf) stageB(cur, t + 2, 1);
    MIDBAR_SEQ();
    QUAD(1, 1, bf1);
    ENDBAR_SEQ();
    if (pf) {
      stageA(cur, t + 2, 1);
      if constexpr (BM == 256) asm volatile("s_waitcnt vmcnt(8)" ::: "memory");
      else                     asm volatile("s_waitcnt vmcnt(6)" ::: "memory");
    } else {
      asm volatile("s_waitcnt vmcnt(0)" ::: "memory");
    }
    MIDBAR_SEQ();
    QUAD(1, 0, bf0);
    ENDBAR_SEQ();
  }

#pragma unroll
  for (int m = 0; m < MR; ++m) {
#pragma unroll
    for (int n = 0; n < 4; ++n) {
      int row = m0 + wm * (BM / 2) + m * 16 + g * 4;
      int col = n0 + wn * 64 + n * 16 + li;
#pragma unroll
      for (int r = 0; r < 4; ++r) {
        if (OUT_F32)
          reinterpret_cast<float*>(Cout)[(size_t)(row + r) * N + col] = acc[m][n][r];
        else
          reinterpret_cast<unsigned short*>(Cout)[(size_t)(row + r) * N + col] =
              f2b(acc[m][n][r]);
      }
    }
  }
}

#undef MIDBAR_SEQ
#undef ENDBAR_SEQ
#undef READA
#undef READB
#undef QUAD

// ---------------- causal flash attention v11: v10 + defer-max (T13) --------
__global__ __launch_bounds__(256) void flash_attn_k(
    const unsigned short* __restrict__ q, const unsigned short* __restrict__ k,
    const unsigned short* __restrict__ vt, unsigned short* __restrict__ o) {
  __shared__ unsigned short Ks[2][2][32 * 128];  // [parity][buf] 32 KB
  __shared__ unsigned short Vs[2][2][128 * 32];  // [parity][buf] 32 KB

  int L = blockIdx.x;
  int xcd = L & 7, j = L >> 3;
  int h = 2 * xcd + (j & 1);
  int qt = (j < 32) ? (31 - (j >> 1)) : ((j - 32) >> 1);  // LPT

  int t = threadIdx.x, wave = t >> 6, l = t & 63;
  int l5 = l >> 5, l31 = l & 31;
  int par = wave >> 1, qh = wave & 1;
  int q0 = qt * 64;
  int q_abs = q0 + qh * 32 + l31;

  const unsigned short* vth = vt + (size_t)h * HDIM * S_LEN;

  auto stage = [&](int buf, int it) {
#pragma unroll
    for (int p2 = 0; p2 < 2; ++p2) {
      int kv0 = it * 64 + p2 * 32;
#pragma unroll
      for (int i = 0; i < 2; ++i) {
        int ch = i * 256 + t;
        int row = ch >> 4, c = ch & 15;
        gload_lds16(k + (size_t)(kv0 + row) * DMODEL + h * HDIM + ((c ^ (row & 7)) * 8),
                    &Ks[p2][buf][ch * 8]);
      }
#pragma unroll
      for (int i = 0; i < 2; ++i) {
        int ch = i * 256 + t;
        int row = ch >> 2, c = ch & 3;
        gload_lds16(vth + (size_t)row * S_LEN + kv0 + ((c ^ (row & 3)) * 8),
                    &Vs[p2][buf][ch * 8]);
      }
    }
  };

  bf16x8 qf[8];
#pragma unroll
  for (int kb = 0; kb < 8; ++kb)
    qf[kb] = *reinterpret_cast<const bf16x8*>(
        q + (size_t)q_abs * DMODEL + h * HDIM + kb * 16 + l5 * 8);

  f32x16 OT[4];
#pragma unroll
  for (int nf = 0; nf < 4; ++nf)
#pragma unroll
    for (int r = 0; r < 16; ++r) OT[nf][r] = 0.f;
  float m_r = -1e30f, l_r = 0.f;

  int nIter = qt + 1;
  stage(0, 0);

  for (int it = 0; it < nIter; ++it) {
    int cur = it & 1;
    if (it + 1 < nIter) {
      stage(cur ^ 1, it + 1);
      asm volatile("s_waitcnt vmcnt(8)" ::: "memory");
    } else {
      asm volatile("s_waitcnt vmcnt(0)" ::: "memory");
    }
    __builtin_amdgcn_s_barrier();
    asm volatile("" ::: "memory");

    int kv0 = it * 64 + par * 32;
    f32x16 sf;
#pragma unroll
    for (int r = 0; r < 16; ++r) sf[r] = 0.f;
#pragma unroll
    for (int kb = 0; kb < 8; ++kb) {
      int c = (2 * kb + l5) ^ (l31 & 7);
      bf16x8 kf = *reinterpret_cast<const bf16x8*>(&Ks[par][cur][(l31 * 16 + c) * 8]);
      sf = __builtin_amdgcn_mfma_f32_32x32x16_bf16(kf, qf[kb], sf, 0, 0, 0);
    }
    if (it == qt) {
#pragma unroll
      for (int r = 0; r < 16; ++r) {
        int kv_abs = kv0 + (r & 3) + 8 * (r >> 2) + 4 * l5;
        if (kv_abs > q_abs) sf[r] = -1e30f;
      }
    }
    float pm = -1e30f;
#pragma unroll
    for (int r = 0; r < 16; ++r) pm = fmaxf(pm, sf[r]);
    pm = fmaxf(pm, __shfl_xor(pm, 32));
    // T13 defer-max: skip rescale when the tile max is within THR of the
    // running max (P bounded by 2^8; f32 l/O headroom is ample).
    if (!__all(pm - m_r <= 8.0f)) {
      float nm = fmaxf(m_r, pm);
      float alpha = exp2f(m_r - nm);
      m_r = nm;
      l_r *= alpha;
#pragma unroll
      for (int nf = 0; nf < 4; ++nf)
#pragma unroll
        for (int r = 0; r < 16; ++r) OT[nf][r] *= alpha;
    }
    float ls = 0.f;
#pragma unroll
    for (int r = 0; r < 16; ++r) {
      float pv = exp2f(sf[r] - m_r);
      sf[r] = pv;
      ls += pv;
    }
    l_r += ls + __shfl_xor(ls, 32);

    bf16x8 pf[2];
#pragma unroll
    for (int ks = 0; ks < 2; ++ks) {
      const int m0 = 8 * ks;
      unsigned A0, A1, B0, B1;
      asm("v_cvt_pk_bf16_f32 %0, %1, %2" : "=v"(A0) : "v"(sf[m0 + 0]), "v"(sf[m0 + 1]));
      asm("v_cvt_pk_bf16_f32 %0, %1, %2" : "=v"(A1) : "v"(sf[m0 + 2]), "v"(sf[m0 + 3]));
      asm("v_cvt_pk_bf16_f32 %0, %1, %2" : "=v"(B0) : "v"(sf[m0 + 4]), "v"(sf[m0 + 5]));
      asm("v_cvt_pk_bf16_f32 %0, %1, %2" : "=v"(B1) : "v"(sf[m0 + 6]), "v"(sf[m0 + 7]));
      unsigned rA0 = (unsigned)__shfl_xor((int)A0, 32);
      unsigned rA1 = (unsigned)__shfl_xor((int)A1, 32);
      unsigned rB0 = (unsigned)__shfl_xor((int)B0, 32);
      unsigned rB1 = (unsigned)__shfl_xor((int)B1, 32);
      union { unsigned u[4]; bf16x8 v; } pk;
      pk.u[0] = l5 ? rB0 : A0;
      pk.u[1] = l5 ? rB1 : A1;
      pk.u[2] = l5 ? B0 : rA0;
      pk.u[3] = l5 ? B1 : rA1;
      pf[ks] = pk.v;
    }

#pragma unroll
    for (int ks = 0; ks < 2; ++ks) {
#pragma unroll
      for (int nf = 0; nf < 4; ++nf) {
        int row = nf * 32 + l31;
        int c = (2 * ks + l5) ^ (row & 3);
        bf16x8 vf = *reinterpret_cast<const bf16x8*>(&Vs[par][cur][(row * 4 + c) * 8]);
        OT[nf] = __builtin_amdgcn_mfma_f32_32x32x16_bf16(vf, pf[ks], OT[nf], 0, 0, 0);
      }
    }
    __builtin_amdgcn_s_barrier();
    asm volatile("" ::: "memory");
  }

  // ---- kv-parity merge + transpose + coalesced store ----
  float* MS = (float*)&Ks[0][0][0];
  float* ML = MS + 8192;
  if (par == 1) {
#pragma unroll
    for (int nf = 0; nf < 4; ++nf)
#pragma unroll
      for (int r = 0; r < 16; ++r) {
        int d = nf * 32 + (r & 3) + 8 * (r >> 2) + 4 * l5;
        MS[qh * 4096 + d * 32 + l31] = OT[nf][r];
      }
    if (l < 32) { ML[qh * 64 + l31] = m_r; ML[qh * 64 + 32 + l31] = l_r; }
  }
  __builtin_amdgcn_s_barrier();
  asm volatile("" ::: "memory");
  if (par == 0) {
    float mB = ML[qh * 64 + l31], lB = ML[qh * 64 + 32 + l31];
    float ms = fmaxf(m_r, mB);
    float eA = exp2f(m_r - ms), eB = exp2f(mB - ms);
    float inv = 1.0f / (l_r * eA + lB * eB);
#pragma unroll
    for (int nf = 0; nf < 4; ++nf)
#pragma unroll
      for (int r = 0; r < 16; ++r) {
        int d = nf * 32 + (r & 3) + 8 * (r >> 2) + 4 * l5;
        OT[nf][r] = (OT[nf][r] * eA + MS[qh * 4096 + d * 32 + l31] * eB) * inv;
      }
  }
  __builtin_amdgcn_s_barrier();
  asm volatile("" ::: "memory");
  if (par == 0) {
#pragma unroll
    for (int nf = 0; nf < 4; ++nf)
#pragma unroll
      for (int r = 0; r < 16; ++r) {
        int d = nf * 32 + (r & 3) + 8 * (r >> 2) + 4 * l5;
        MS[qh * 4096 + d * 32 + l31] = OT[nf][r];
      }
  }
  __builtin_amdgcn_s_barrier();
  asm volatile("" ::: "memory");
  {
    int qq = t >> 2;
    int dg = (t & 3) * 32;
    const float* src = MS + (qq >> 5) * 4096 + (qq & 31);
    unsigned pk[16];
#pragma unroll
    for (int i = 0; i < 16; ++i) {
      unsigned lo = f2b(src[(dg + 2 * i) * 32]);
      unsigned hi = f2b(src[(dg + 2 * i + 1) * 32]);
      pk[i] = lo | (hi << 16);
    }
    unsigned short* op = o + (size_t)(q0 + qq) * DMODEL + h * HDIM + dg;
#pragma unroll
    for (int i = 0; i < 4; ++i) {
      uint4 w = make_uint4(pk[4 * i], pk[4 * i + 1], pk[4 * i + 2], pk[4 * i + 3]);
      *reinterpret_cast<uint4*>(op + i * 8) = w;
    }
  }
}

extern "C" void kernel_launch(void* const* d_in, const int* in_sizes, int n_in,
                              void* d_out, int out_size, void* d_ws, size_t ws_size,
                              hipStream_t stream) {
  const float* hs = (const float*)d_in[0];
  const float* Wq = (const float*)d_in[1];
  const float* Wk = (const float*)d_in[2];
  const float* Wv = (const float*)d_in[3];
  const float* Wo = (const float*)d_in[4];

  char* ws = (char*)d_ws;
  const size_t MB = 1024 * 1024;
  unsigned short* hs_b = (unsigned short*)(ws + 0 * MB);  // reused as vt later
  unsigned short* Wq_b = (unsigned short*)(ws + 8 * MB);
  unsigned short* Wk_b = (unsigned short*)(ws + 16 * MB);
  unsigned short* Wv_b = (unsigned short*)(ws + 24 * MB);
  unsigned short* Wo_b = (unsigned short*)(ws + 32 * MB);
  unsigned short* qb = (unsigned short*)(ws + 40 * MB);
  unsigned short* kb = (unsigned short*)(ws + 48 * MB);
  unsigned short* vb = (unsigned short*)(ws + 56 * MB);
  unsigned short* ab = (unsigned short*)(ws + 64 * MB);
  float* cs = (float*)(ws + 72 * MB);
  float* sn = (float*)(ws + 72 * MB + 512 * 1024);
  unsigned short* vtb = hs_b;  // V^T [h][d][s]; hs_b dead after QKV GEMM
  float* P0 = (float*)(ws + 8 * MB);   // Wq_b/Wk_b dead at Wo time
  float* P1 = (float*)(ws + 40 * MB);  // qb/kb dead at Wo time

  cvt5_f32_bf16_k<<<(5 * 1024 * 1024) / 256, 256, 0, stream>>>(
      hs, Wq, Wk, Wv, Wo, hs_b, Wq_b, Wk_b, Wv_b, Wo_b);

  rope_table_k<<<(S_LEN * 64) / 256, 256, 0, stream>>>(cs, sn);

  gemm_8ph_k<256, false><<<dim3(64, 1, 3), 512, 0, stream>>>(
      hs_b, Wq_b, Wk_b, Wv_b, qb, kb, vb, 2048, 2048, 2048, 2048, 0);

  transpose_bf16_k<<<dim3(32, 32), 256, 0, stream>>>(vb, vtb);

  rope_apply_k<<<(S_LEN * NHEADS * 64) / 256, 256, 0, stream>>>(qb, kb, cs, sn);

  flash_attn_k<<<dim3(512), 256, 0, stream>>>(qb, kb, vtb, ab);

  gemm_8ph_k<128, true><<<dim3(128, 1, 2), 512, 0, stream>>>(
      ab, Wo_b, Wo_b + 1024, Wo_b, P0, P1, P0, 2048, 2048, 1024, 2048, 1024);
  addf2_k<<<(2048 * 2048) / 1024, 256, 0, stream>>>(P0, P1, (float*)d_out);
}